// Round 6
// baseline (390.136 us; speedup 1.0000x reference)
//
#include <hip/hip_runtime.h>
#include <hip/hip_bf16.h>

#define FEAT 64

typedef __bf16 bf16x8 __attribute__((ext_vector_type(8)));
typedef __bf16 bf16x4 __attribute__((ext_vector_type(4)));
typedef float  f32x4  __attribute__((ext_vector_type(4)));

// ---------------------------------------------------------------------------
// Zero int buffers via kernel (hipMemsetAsync may run at capture time, not as
// a graph node -> poisoned on replay; learned in R2).
// ---------------------------------------------------------------------------
__global__ __launch_bounds__(256)
void zero2_kernel(int* __restrict__ a, int* __restrict__ b, int n) {
    int i = blockIdx.x * 256 + threadIdx.x;
    if (i < n) { a[i] = 0; b[i] = 0; }
}

// ---------------------------------------------------------------------------
// int64-vs-int32 edge_index sniffer (flag=1 if int64).
// ---------------------------------------------------------------------------
__global__ void detect_idx_kernel(const unsigned* __restrict__ w, int* __restrict__ flag) {
    __shared__ int any_nz;
    if (threadIdx.x == 0) any_nz = 0;
    __syncthreads();
    if (w[2 * threadIdx.x + 1] != 0u) atomicOr(&any_nz, 1);  // first 2KB only
    __syncthreads();
    if (threadIdx.x == 0) *flag = (any_nz == 0) ? 1 : 0;
}

__device__ __forceinline__ int load_idx_clamped(const void* ei, long long i, int is64, int n_nodes) {
    int v = is64 ? (int)((const long long*)ei)[i] : ((const int*)ei)[i];
    v = v < 0 ? 0 : v;
    return v >= n_nodes ? n_nodes - 1 : v;   // identity when data is sane
}

// ---------------------------------------------------------------------------
// T1: compact dst -> clamped int32 (sequential read+write, cheap). Replaces
// R5's dr buffer byte-for-byte, so T1 workspace need is unchanged (proven fit).
// ---------------------------------------------------------------------------
__global__ __launch_bounds__(256)
void compact_dst_kernel(const void* __restrict__ ei, const int* __restrict__ flagp,
                        int* __restrict__ dst32, int n_edges, int n_nodes) {
    int e = blockIdx.x * 256 + threadIdx.x;
    if (e >= n_edges) return;
    dst32[e] = load_idx_clamped(ei, (long long)n_edges + e, *flagp, n_nodes);
}

// ---------------------------------------------------------------------------
// T1 histogram, XCD-sliced: block j=blockIdx&7 owns dst slice j. All atomics
// land in that slice's ~50KB of degc -> L2-local, no cross-XCD RMW lines.
// Each slice streams the whole dst32 (L3-resident) with nt loads.
// ---------------------------------------------------------------------------
__global__ __launch_bounds__(256)
void hist_xcd_kernel(const int* __restrict__ dst32, int* __restrict__ degc,
                     int n_edges, int n_nodes) {
    const int j = blockIdx.x & 7;
    const int slice = (n_nodes + 7) >> 3;
    const int lo = j * slice, hi = min(n_nodes, lo + slice);
    const int nchunks = (n_edges + 255) >> 8, step = gridDim.x >> 3;
    for (int c = blockIdx.x >> 3; c < nchunks; c += step) {
        int e = c * 256 + threadIdx.x;
        if (e >= n_edges) continue;
        int d = __builtin_nontemporal_load(&dst32[e]);
        if (d >= lo && d < hi) atomicAdd(&degc[d], 1);
    }
}

// ---------------------------------------------------------------------------
// Scans (shared by all paths)
// ---------------------------------------------------------------------------
__global__ __launch_bounds__(256)
void scan_partial_kernel(const int* __restrict__ degc, int* __restrict__ part, int n_nodes) {
    __shared__ int sh[256];
    int i = blockIdx.x * 256 + threadIdx.x;
    sh[threadIdx.x] = (i < n_nodes) ? degc[i] : 0;
    __syncthreads();
    for (int off = 128; off > 0; off >>= 1) {
        if (threadIdx.x < off) sh[threadIdx.x] += sh[threadIdx.x + off];
        __syncthreads();
    }
    if (threadIdx.x == 0) part[blockIdx.x] = sh[0];
}

__global__ void scan_top_kernel(int* __restrict__ part, int nparts) {
    __shared__ int sh[512];
    int t = threadIdx.x;
    int v = (t < nparts) ? part[t] : 0;
    sh[t] = v;
    __syncthreads();
    for (int off = 1; off < 512; off <<= 1) {
        int u = (t >= off) ? sh[t - off] : 0;
        __syncthreads();
        sh[t] += u;
        __syncthreads();
    }
    if (t < nparts) part[t] = sh[t] - v;   // exclusive
}

__global__ __launch_bounds__(256)
void scan_final_kernel(const int* __restrict__ degc, const int* __restrict__ part,
                       int* __restrict__ offs, float* __restrict__ deg_inv, int n_nodes) {
    __shared__ int sh[256];
    int t = threadIdx.x;
    int i = blockIdx.x * 256 + t;
    int v = (i < n_nodes) ? degc[i] : 0;
    sh[t] = v;
    __syncthreads();
    for (int off = 1; off < 256; off <<= 1) {
        int u = (t >= off) ? sh[t - off] : 0;
        __syncthreads();
        sh[t] += u;
        __syncthreads();
    }
    if (i < n_nodes) {
        offs[i]    = sh[t] - v + part[blockIdx.x];
        deg_inv[i] = 1.0f / fmaxf((float)v, 1.0f);
    }
}

// ---------------------------------------------------------------------------
// T1 scatter, XCD-sliced cursor atomics. Ranks need only be UNIQUE per dst
// (mean is permutation-invariant), so per-slice cursor atomics are enough —
// cursor slice AND the contiguous csr[offs[lo]..offs[hi)) output range are
// both XCD-local -> writes merge in L2. src loaded conditionally from ei.
// ---------------------------------------------------------------------------
__global__ __launch_bounds__(256)
void scatter_xcd2_kernel(const void* __restrict__ ei, const int* __restrict__ flagp,
                         const int* __restrict__ dst32, const int* __restrict__ offs,
                         int* __restrict__ cursor, int* __restrict__ csr,
                         int n_edges, int n_nodes) {
    const int j = blockIdx.x & 7;
    const int slice = (n_nodes + 7) >> 3;
    const int lo = j * slice, hi = min(n_nodes, lo + slice);
    const int is64 = *flagp;
    const int nchunks = (n_edges + 255) >> 8, step = gridDim.x >> 3;
    for (int c = blockIdx.x >> 3; c < nchunks; c += step) {
        int e = c * 256 + threadIdx.x;
        if (e >= n_edges) continue;
        int d = __builtin_nontemporal_load(&dst32[e]);
        if (d >= lo && d < hi) {
            int s = load_idx_clamped(ei, e, is64, n_nodes);
            int pos = offs[d] + atomicAdd(&cursor[d], 1);
            pos = pos < 0 ? 0 : (pos >= n_edges ? n_edges - 1 : pos);
            csr[pos] = s;
        }
    }
}

// ---------------------------------------------------------------------------
// T3 path (R4, proven): global-atomic hist + cursor scatter.
// ---------------------------------------------------------------------------
__global__ __launch_bounds__(256)
void hist_kernel(const void* __restrict__ ei, const int* __restrict__ flagp,
                 int* __restrict__ degc, int n_edges, int n_nodes) {
    int e = blockIdx.x * 256 + threadIdx.x;
    if (e >= n_edges) return;
    int d = load_idx_clamped(ei, (long long)n_edges + e, *flagp, n_nodes);
    atomicAdd(&degc[d], 1);
}

__global__ __launch_bounds__(256)
void csr_scatter_kernel(const void* __restrict__ ei, const int* __restrict__ flagp,
                        const int* __restrict__ offs, int* __restrict__ cursor,
                        int* __restrict__ csr, int n_edges, int n_nodes) {
    int e = blockIdx.x * 256 + threadIdx.x;
    if (e >= n_edges) return;
    int is64 = *flagp;
    int s = load_idx_clamped(ei, e, is64, n_nodes);
    int d = load_idx_clamped(ei, (long long)n_edges + e, is64, n_nodes);
    int pos = offs[d] + atomicAdd(&cursor[d], 1);
    pos = pos < 0 ? 0 : (pos >= n_edges ? n_edges - 1 : pos);
    csr[pos] = s;
}

// ---------------------------------------------------------------------------
// Casts
// ---------------------------------------------------------------------------
__global__ __launch_bounds__(256)
void cast_w_kernel(const float* __restrict__ a, const float* __restrict__ b,
                   const float* __restrict__ c, const float* __restrict__ d,
                   __bf16* __restrict__ o) {
    int i = blockIdx.x * 256 + threadIdx.x;
    if (i < FEAT * FEAT) {
        o[i]         = (__bf16)a[i];
        o[4096 + i]  = (__bf16)b[i];
        o[8192 + i]  = (__bf16)c[i];
        o[12288 + i] = (__bf16)d[i];
    }
}

__global__ __launch_bounds__(256)
void cast_x_kernel(const float* __restrict__ x, __bf16* __restrict__ xb, int n4) {
    int i = blockIdx.x * 256 + threadIdx.x;
    if (i < n4) {
        float4 v = ((const float4*)x)[i];
        bf16x4 o;
        o.x = (__bf16)v.x; o.y = (__bf16)v.y; o.z = (__bf16)v.z; o.w = (__bf16)v.w;
        ((bf16x4*)xb)[i] = o;
    }
}

// ---------------------------------------------------------------------------
// Gather kernels: wave per node, no LDS; 4 groups of 16 lanes = 4 independent
// chains; butterfly merge; group 0 stores mean row bf16x4.
// ---------------------------------------------------------------------------
__global__ __launch_bounds__(256)
void gather_f32_kernel(const float* __restrict__ xin, const int* __restrict__ offs,
                       const int* __restrict__ degc, const float* __restrict__ dinv,
                       const int* __restrict__ csr, __bf16* __restrict__ agg,
                       int n_nodes) {
    const int t = threadIdx.x, lane = t & 63, g = lane >> 4, u = lane & 15;
    const int gw = blockIdx.x * 4 + (t >> 6), nw = gridDim.x * 4;
    for (int n = gw; n < n_nodes; n += nw) {
        int rs = offs[n], cnt = degc[n];
        float a0 = 0.f, a1 = 0.f, a2 = 0.f, a3 = 0.f;
        for (int c = 0; c < cnt; c += 64) {
            int chunk = min(64, cnt - c);
            int myid = (lane < chunk) ? csr[rs + c + lane] : 0;
            myid = myid < 0 ? 0 : (myid >= n_nodes ? n_nodes - 1 : myid);
            for (int q = 0; q < chunk; q += 4) {
                int qq = q + g;
                int s = __shfl(myid, qq);
                if (qq < chunk) {
                    const float4 v = ((const float4*)xin)[(size_t)s * 16 + u];
                    a0 += v.x; a1 += v.y; a2 += v.z; a3 += v.w;
                }
            }
        }
        a0 += __shfl_xor(a0, 16); a1 += __shfl_xor(a1, 16);
        a2 += __shfl_xor(a2, 16); a3 += __shfl_xor(a3, 16);
        a0 += __shfl_xor(a0, 32); a1 += __shfl_xor(a1, 32);
        a2 += __shfl_xor(a2, 32); a3 += __shfl_xor(a3, 32);
        if (g == 0) {
            float di = dinv[n];
            bf16x4 o;
            o.x = (__bf16)(a0 * di); o.y = (__bf16)(a1 * di);
            o.z = (__bf16)(a2 * di); o.w = (__bf16)(a3 * di);
            ((bf16x4*)agg)[(size_t)n * 16 + u] = o;
        }
    }
}

__global__ __launch_bounds__(256)
void gather_bf16_kernel(const __bf16* __restrict__ hin, const int* __restrict__ offs,
                        const int* __restrict__ degc, const float* __restrict__ dinv,
                        const int* __restrict__ csr, __bf16* __restrict__ agg,
                        int n_nodes) {
    const int t = threadIdx.x, lane = t & 63, g = lane >> 4, u = lane & 15;
    const int gw = blockIdx.x * 4 + (t >> 6), nw = gridDim.x * 4;
    for (int n = gw; n < n_nodes; n += nw) {
        int rs = offs[n], cnt = degc[n];
        float a0 = 0.f, a1 = 0.f, a2 = 0.f, a3 = 0.f;
        for (int c = 0; c < cnt; c += 64) {
            int chunk = min(64, cnt - c);
            int myid = (lane < chunk) ? csr[rs + c + lane] : 0;
            myid = myid < 0 ? 0 : (myid >= n_nodes ? n_nodes - 1 : myid);
            for (int q = 0; q < chunk; q += 4) {
                int qq = q + g;
                int s = __shfl(myid, qq);
                if (qq < chunk) {
                    const bf16x4 v = ((const bf16x4*)hin)[(size_t)s * 16 + u];
                    a0 += (float)v.x; a1 += (float)v.y; a2 += (float)v.z; a3 += (float)v.w;
                }
            }
        }
        a0 += __shfl_xor(a0, 16); a1 += __shfl_xor(a1, 16);
        a2 += __shfl_xor(a2, 16); a3 += __shfl_xor(a3, 16);
        a0 += __shfl_xor(a0, 32); a1 += __shfl_xor(a1, 32);
        a2 += __shfl_xor(a2, 32); a3 += __shfl_xor(a3, 32);
        if (g == 0) {
            float di = dinv[n];
            bf16x4 o;
            o.x = (__bf16)(a0 * di); o.y = (__bf16)(a1 * di);
            o.z = (__bf16)(a2 * di); o.w = (__bf16)(a3 * di);
            ((bf16x4*)agg)[(size_t)n * 16 + u] = o;
        }
    }
}

// ---------------------------------------------------------------------------
// MFMA GEMMs (16x16x32 bf16; verified fragment layouts).
// ---------------------------------------------------------------------------
__global__ __launch_bounds__(256)
void gemm_l1b_kernel(const __bf16* __restrict__ Ag, const __bf16* __restrict__ xb,
                     const __bf16* __restrict__ Bl, const __bf16* __restrict__ Br,
                     const float* __restrict__ bias,
                     __bf16* __restrict__ hout, int n_nodes) {
    const int t = threadIdx.x, lane = t & 63;
    const int quad = lane >> 4, r16 = lane & 15;
    bf16x8 bl[2][4], br[2][4];
    #pragma unroll
    for (int ks = 0; ks < 2; ++ks)
        #pragma unroll
        for (int ct = 0; ct < 4; ++ct) {
            int f = ct * 16 + r16, k = ks * 32 + quad * 8;
            bl[ks][ct] = *(const bf16x8*)(Bl + f * 64 + k);
            br[ks][ct] = *(const bf16x8*)(Br + f * 64 + k);
        }
    const int m0 = (blockIdx.x * 4 + (t >> 6)) * 16;
    if (m0 >= n_nodes) return;
    int mrow = m0 + r16; if (mrow >= n_nodes) mrow = n_nodes - 1;
    bf16x8 ag[2], ax[2];
    #pragma unroll
    for (int ks = 0; ks < 2; ++ks) {
        ag[ks] = *(const bf16x8*)(Ag + (size_t)mrow * 64 + ks * 32 + quad * 8);
        ax[ks] = *(const bf16x8*)(xb + (size_t)mrow * 64 + ks * 32 + quad * 8);
    }
    #pragma unroll
    for (int ct = 0; ct < 4; ++ct) {
        f32x4 acc = {0.f, 0.f, 0.f, 0.f};
        acc = __builtin_amdgcn_mfma_f32_16x16x32_bf16(ag[0], bl[0][ct], acc, 0, 0, 0);
        acc = __builtin_amdgcn_mfma_f32_16x16x32_bf16(ag[1], bl[1][ct], acc, 0, 0, 0);
        acc = __builtin_amdgcn_mfma_f32_16x16x32_bf16(ax[0], br[0][ct], acc, 0, 0, 0);
        acc = __builtin_amdgcn_mfma_f32_16x16x32_bf16(ax[1], br[1][ct], acc, 0, 0, 0);
        int col = ct * 16 + r16;
        float bv = bias[col];
        #pragma unroll
        for (int rg = 0; rg < 4; ++rg) {
            int n = m0 + quad * 4 + rg;
            if (n < n_nodes) {
                float o = acc[rg] + bv;
                hout[(size_t)n * 64 + col] = (__bf16)fmaxf(o, 0.f);
            }
        }
    }
}

__global__ __launch_bounds__(256)
void gemm_l1_kernel(const __bf16* __restrict__ Ag, const float* __restrict__ xin,
                    const __bf16* __restrict__ Bl, const __bf16* __restrict__ Br,
                    const float* __restrict__ bias,
                    __bf16* __restrict__ hout, int n_nodes) {
    const int t = threadIdx.x, lane = t & 63;
    const int quad = lane >> 4, r16 = lane & 15;
    bf16x8 bl[2][4], br[2][4];
    #pragma unroll
    for (int ks = 0; ks < 2; ++ks)
        #pragma unroll
        for (int ct = 0; ct < 4; ++ct) {
            int f = ct * 16 + r16, k = ks * 32 + quad * 8;
            bl[ks][ct] = *(const bf16x8*)(Bl + f * 64 + k);
            br[ks][ct] = *(const bf16x8*)(Br + f * 64 + k);
        }
    const int m0 = (blockIdx.x * 4 + (t >> 6)) * 16;
    if (m0 >= n_nodes) return;
    int mrow = m0 + r16; if (mrow >= n_nodes) mrow = n_nodes - 1;
    bf16x8 ag[2], ax[2];
    #pragma unroll
    for (int ks = 0; ks < 2; ++ks) {
        ag[ks] = *(const bf16x8*)(Ag + (size_t)mrow * 64 + ks * 32 + quad * 8);
        const float* xr = xin + (size_t)mrow * 64 + ks * 32 + quad * 8;
        float4 p = *(const float4*)xr;
        float4 q = *(const float4*)(xr + 4);
        union { bf16x8 v; __bf16 e[8]; } U;
        U.e[0] = (__bf16)p.x; U.e[1] = (__bf16)p.y; U.e[2] = (__bf16)p.z; U.e[3] = (__bf16)p.w;
        U.e[4] = (__bf16)q.x; U.e[5] = (__bf16)q.y; U.e[6] = (__bf16)q.z; U.e[7] = (__bf16)q.w;
        ax[ks] = U.v;
    }
    #pragma unroll
    for (int ct = 0; ct < 4; ++ct) {
        f32x4 acc = {0.f, 0.f, 0.f, 0.f};
        acc = __builtin_amdgcn_mfma_f32_16x16x32_bf16(ag[0], bl[0][ct], acc, 0, 0, 0);
        acc = __builtin_amdgcn_mfma_f32_16x16x32_bf16(ag[1], bl[1][ct], acc, 0, 0, 0);
        acc = __builtin_amdgcn_mfma_f32_16x16x32_bf16(ax[0], br[0][ct], acc, 0, 0, 0);
        acc = __builtin_amdgcn_mfma_f32_16x16x32_bf16(ax[1], br[1][ct], acc, 0, 0, 0);
        int col = ct * 16 + r16;
        float bv = bias[col];
        #pragma unroll
        for (int rg = 0; rg < 4; ++rg) {
            int n = m0 + quad * 4 + rg;
            if (n < n_nodes) {
                float o = acc[rg] + bv;
                hout[(size_t)n * 64 + col] = (__bf16)fmaxf(o, 0.f);
            }
        }
    }
}

__global__ __launch_bounds__(256)
void gemm_l2_kernel(const __bf16* __restrict__ Ag, const __bf16* __restrict__ Ah,
                    const __bf16* __restrict__ Bl, const __bf16* __restrict__ Br,
                    const float* __restrict__ bias,
                    float* __restrict__ out, int n_nodes) {
    const int t = threadIdx.x, lane = t & 63;
    const int quad = lane >> 4, r16 = lane & 15;
    bf16x8 bl[2][4], br[2][4];
    #pragma unroll
    for (int ks = 0; ks < 2; ++ks)
        #pragma unroll
        for (int ct = 0; ct < 4; ++ct) {
            int f = ct * 16 + r16, k = ks * 32 + quad * 8;
            bl[ks][ct] = *(const bf16x8*)(Bl + f * 64 + k);
            br[ks][ct] = *(const bf16x8*)(Br + f * 64 + k);
        }
    const int m0 = (blockIdx.x * 4 + (t >> 6)) * 16;
    if (m0 >= n_nodes) return;
    int mrow = m0 + r16; if (mrow >= n_nodes) mrow = n_nodes - 1;
    bf16x8 ag[2], ah[2];
    #pragma unroll
    for (int ks = 0; ks < 2; ++ks) {
        ag[ks] = *(const bf16x8*)(Ag + (size_t)mrow * 64 + ks * 32 + quad * 8);
        ah[ks] = *(const bf16x8*)(Ah + (size_t)mrow * 64 + ks * 32 + quad * 8);
    }
    #pragma unroll
    for (int ct = 0; ct < 4; ++ct) {
        f32x4 acc = {0.f, 0.f, 0.f, 0.f};
        acc = __builtin_amdgcn_mfma_f32_16x16x32_bf16(ag[0], bl[0][ct], acc, 0, 0, 0);
        acc = __builtin_amdgcn_mfma_f32_16x16x32_bf16(ag[1], bl[1][ct], acc, 0, 0, 0);
        acc = __builtin_amdgcn_mfma_f32_16x16x32_bf16(ah[0], br[0][ct], acc, 0, 0, 0);
        acc = __builtin_amdgcn_mfma_f32_16x16x32_bf16(ah[1], br[1][ct], acc, 0, 0, 0);
        int col = ct * 16 + r16;
        float bv = bias[col];
        #pragma unroll
        for (int rg = 0; rg < 4; ++rg) {
            int n = m0 + quad * 4 + rg;
            if (n < n_nodes) out[(size_t)n * 64 + col] = acc[rg] + bv;
        }
    }
}

// ---------------------------------------------------------------------------
// T4 fallback (R3): fused LDS kernels.
// ---------------------------------------------------------------------------
__global__ __launch_bounds__(256)
void sage_fused_l1_kernel(const float* __restrict__ xin,
                          const int* __restrict__ offs, const int* __restrict__ degc,
                          const float* __restrict__ deg_inv, const int* __restrict__ csr,
                          const float* __restrict__ Wl, const float* __restrict__ bias,
                          const float* __restrict__ Wr,
                          __bf16* __restrict__ hout, int n_nodes) {
    __shared__ float WlT[FEAT * 65], WrT[FEAT * 65], bsh[FEAT];
    __shared__ float aggS[4][FEAT], selfS[4][FEAT];
    const int t = threadIdx.x;
    #pragma unroll
    for (int p = 0; p < 16; ++p) {
        int i = t + p * 256, j = i >> 6, k = i & 63;
        WlT[k * 65 + j] = Wl[i];
        WrT[k * 65 + j] = Wr[i];
    }
    if (t < FEAT) bsh[t] = bias[t];
    __syncthreads();
    const int w = t >> 6, f = t & 63;
    const int n_groups = (n_nodes + 3) >> 2;
    for (int g = blockIdx.x; g < n_groups; g += gridDim.x) {
        int n = g * 4 + w;
        bool act = (n < n_nodes);
        if (act) {
            int rs = offs[n], cnt = degc[n];
            float acc = 0.f;
            for (int c = 0; c < cnt; c += 64) {
                int chunk = min(64, cnt - c);
                int myid = (f < chunk) ? csr[rs + c + f] : 0;
                #pragma unroll 4
                for (int q = 0; q < chunk; ++q) {
                    int s = __shfl(myid, q);
                    acc += xin[(long long)s * FEAT + f];
                }
            }
            aggS[w][f]  = acc * deg_inv[n];
            selfS[w][f] = xin[(long long)n * FEAT + f];
        }
        __syncthreads();
        if (act) {
            float o = bsh[f];
            #pragma unroll
            for (int k = 0; k < FEAT; ++k) {
                o = fmaf(aggS[w][k],  WlT[k * 65 + f], o);
                o = fmaf(selfS[w][k], WrT[k * 65 + f], o);
            }
            o = fmaxf(o, 0.f);
            hout[(long long)n * FEAT + f] = (__bf16)o;
        }
        __syncthreads();
    }
}

__global__ __launch_bounds__(256)
void sage_fused_l2_kernel(const __bf16* __restrict__ hin,
                          const int* __restrict__ offs, const int* __restrict__ degc,
                          const float* __restrict__ deg_inv, const int* __restrict__ csr,
                          const float* __restrict__ Wl, const float* __restrict__ bias,
                          const float* __restrict__ Wr,
                          float* __restrict__ out, int n_nodes) {
    __shared__ float WlT[FEAT * 65], WrT[FEAT * 65], bsh[FEAT];
    __shared__ float aggS[4][FEAT], selfS[4][FEAT];
    const int t = threadIdx.x;
    #pragma unroll
    for (int p = 0; p < 16; ++p) {
        int i = t + p * 256, j = i >> 6, k = i & 63;
        WlT[k * 65 + j] = Wl[i];
        WrT[k * 65 + j] = Wr[i];
    }
    if (t < FEAT) bsh[t] = bias[t];
    __syncthreads();
    const int w = t >> 6, f = t & 63;
    const int n_groups = (n_nodes + 3) >> 2;
    for (int g = blockIdx.x; g < n_groups; g += gridDim.x) {
        int n = g * 4 + w;
        bool act = (n < n_nodes);
        if (act) {
            int rs = offs[n], cnt = degc[n];
            float acc = 0.f;
            for (int c = 0; c < cnt; c += 64) {
                int chunk = min(64, cnt - c);
                int myid = (f < chunk) ? csr[rs + c + f] : 0;
                #pragma unroll 4
                for (int q = 0; q < chunk; ++q) {
                    int s = __shfl(myid, q);
                    acc += (float)hin[(long long)s * FEAT + f];
                }
            }
            aggS[w][f]  = acc * deg_inv[n];
            selfS[w][f] = (float)hin[(long long)n * FEAT + f];
        }
        __syncthreads();
        if (act) {
            float o = bsh[f];
            #pragma unroll
            for (int k = 0; k < FEAT; ++k) {
                o = fmaf(aggS[w][k],  WlT[k * 65 + f], o);
                o = fmaf(selfS[w][k], WrT[k * 65 + f], o);
            }
            out[(long long)n * FEAT + f] = o;
        }
        __syncthreads();
    }
}

// ---------------------------------------------------------------------------
// Launch
// ---------------------------------------------------------------------------
extern "C" void kernel_launch(void* const* d_in, const int* in_sizes, int n_in,
                              void* d_out, int out_size, void* d_ws, size_t ws_size,
                              hipStream_t stream) {
    const float* x   = (const float*)d_in[0];
    const void*  ei  = d_in[1];
    const float* W1l = (const float*)d_in[2];
    const float* b1  = (const float*)d_in[3];
    const float* W1r = (const float*)d_in[4];
    const float* W2l = (const float*)d_in[5];
    const float* b2  = (const float*)d_in[6];
    const float* W2r = (const float*)d_in[7];
    float* out = (float*)d_out;

    const int n_nodes = in_sizes[0] / FEAT;
    const int n_edges = in_sizes[1] / 2;
    const int nparts  = (n_nodes + 255) / 256;     // <= 512
    const int egrid   = (n_edges + 255) / 256;

    char* ws = (char*)d_ws;
    auto al = [](size_t v) { return (v + 255) & ~(size_t)255; };

    // ---- T1 layout (~52.4 MB, same footprint as R5's proven-fit layout) ----
    size_t o = 0;
    int*    flag   = (int*)(ws + o);      o += 256;
    int*    degc   = (int*)(ws + o);      o += al((size_t)n_nodes * 4);
    float*  dinv   = (float*)(ws + o);    o += al((size_t)n_nodes * 4);
    int*    offs   = (int*)(ws + o);      o += al((size_t)n_nodes * 4);
    int*    cursor = (int*)(ws + o);      o += al((size_t)n_nodes * 4);
    int*    part   = (int*)(ws + o);      o += al(2048);
    int*    dst32  = (int*)(ws + o);      o += al((size_t)n_edges * 4);
    int*    csr    = (int*)(ws + o);      o += al((size_t)n_edges * 4);
    __bf16* xb     = (__bf16*)(ws + o);   o += al((size_t)n_nodes * FEAT * 2);
    __bf16* wb     = (__bf16*)(ws + o);   o += al((size_t)4 * FEAT * FEAT * 2);
    __bf16* agg    = (__bf16*)(ws + o);   o += al((size_t)n_nodes * FEAT * 2);
    __bf16* h      = (__bf16*)(ws + o);   o += al((size_t)n_nodes * FEAT * 2);
    const size_t needT1 = o;

    // ---- T3 layout (R4, ~33.6 MB) ----
    size_t o3 = 0;
    int*    flag3   = (int*)(ws + o3);    o3 += 256;
    int*    degc3   = (int*)(ws + o3);    o3 += al((size_t)n_nodes * 4);
    float*  dinv3   = (float*)(ws + o3);  o3 += al((size_t)n_nodes * 4);
    int*    offs3   = (int*)(ws + o3);    o3 += al((size_t)n_nodes * 4);
    int*    cursor3 = (int*)(ws + o3);    o3 += al((size_t)n_nodes * 4);
    int*    part3   = (int*)(ws + o3);    o3 += al(2048);
    int*    csr3    = (int*)(ws + o3);    o3 += al((size_t)n_edges * 4);
    const size_t commonEnd3 = o3;
    __bf16* wb3  = (__bf16*)(ws + o3);    o3 += al((size_t)4 * FEAT * FEAT * 2);
    __bf16* agg3 = (__bf16*)(ws + o3);    o3 += al((size_t)n_nodes * FEAT * 2);
    __bf16* h3   = (__bf16*)(ws + o3);    o3 += al((size_t)n_nodes * FEAT * 2);
    const size_t needT3 = o3;

    const int n4 = n_nodes * FEAT / 4;
    const int mgrid = (n_nodes + 63) / 64;
    const int ggrid = 2048;
    const int sgrid = 2048;   // multiple of 8 for XCD slicing

    if (ws_size >= needT1) {
        zero2_kernel<<<nparts, 256, 0, stream>>>(degc, cursor, n_nodes);
        detect_idx_kernel<<<1, 256, 0, stream>>>((const unsigned*)ei, flag);
        compact_dst_kernel<<<egrid, 256, 0, stream>>>(ei, flag, dst32, n_edges, n_nodes);
        hist_xcd_kernel<<<sgrid, 256, 0, stream>>>(dst32, degc, n_edges, n_nodes);
        scan_partial_kernel<<<nparts, 256, 0, stream>>>(degc, part, n_nodes);
        scan_top_kernel<<<1, 512, 0, stream>>>(part, nparts);
        scan_final_kernel<<<nparts, 256, 0, stream>>>(degc, part, offs, dinv, n_nodes);
        cast_x_kernel<<<(n4 + 255) / 256, 256, 0, stream>>>(x, xb, n4);
        cast_w_kernel<<<16, 256, 0, stream>>>(W1l, W1r, W2l, W2r, wb);
        scatter_xcd2_kernel<<<sgrid, 256, 0, stream>>>(ei, flag, dst32, offs, cursor, csr, n_edges, n_nodes);
        gather_bf16_kernel<<<ggrid, 256, 0, stream>>>(xb, offs, degc, dinv, csr, agg, n_nodes);
        gemm_l1b_kernel<<<mgrid, 256, 0, stream>>>(agg, xb, wb, wb + 4096, b1, h, n_nodes);
        gather_bf16_kernel<<<ggrid, 256, 0, stream>>>(h, offs, degc, dinv, csr, agg, n_nodes);
        gemm_l2_kernel<<<mgrid, 256, 0, stream>>>(agg, h, wb + 8192, wb + 12288, b2, out, n_nodes);
    } else if (ws_size >= needT3) {
        zero2_kernel<<<nparts, 256, 0, stream>>>(degc3, cursor3, n_nodes);
        detect_idx_kernel<<<1, 256, 0, stream>>>((const unsigned*)ei, flag3);
        hist_kernel<<<egrid, 256, 0, stream>>>(ei, flag3, degc3, n_edges, n_nodes);
        scan_partial_kernel<<<nparts, 256, 0, stream>>>(degc3, part3, n_nodes);
        scan_top_kernel<<<1, 512, 0, stream>>>(part3, nparts);
        scan_final_kernel<<<nparts, 256, 0, stream>>>(degc3, part3, offs3, dinv3, n_nodes);
        csr_scatter_kernel<<<egrid, 256, 0, stream>>>(ei, flag3, offs3, cursor3, csr3, n_edges, n_nodes);
        cast_w_kernel<<<16, 256, 0, stream>>>(W1l, W1r, W2l, W2r, wb3);
        gather_f32_kernel<<<ggrid, 256, 0, stream>>>(x, offs3, degc3, dinv3, csr3, agg3, n_nodes);
        gemm_l1_kernel<<<mgrid, 256, 0, stream>>>(agg3, x, wb3, wb3 + 4096, b1, h3, n_nodes);
        gather_bf16_kernel<<<ggrid, 256, 0, stream>>>(h3, offs3, degc3, dinv3, csr3, agg3, n_nodes);
        gemm_l2_kernel<<<mgrid, 256, 0, stream>>>(agg3, h3, wb3 + 8192, wb3 + 12288, b2, out, n_nodes);
    } else {
        __bf16* hf = (__bf16*)(ws + commonEnd3);
        zero2_kernel<<<nparts, 256, 0, stream>>>(degc3, cursor3, n_nodes);
        detect_idx_kernel<<<1, 256, 0, stream>>>((const unsigned*)ei, flag3);
        hist_kernel<<<egrid, 256, 0, stream>>>(ei, flag3, degc3, n_edges, n_nodes);
        scan_partial_kernel<<<nparts, 256, 0, stream>>>(degc3, part3, n_nodes);
        scan_top_kernel<<<1, 512, 0, stream>>>(part3, nparts);
        scan_final_kernel<<<nparts, 256, 0, stream>>>(degc3, part3, offs3, dinv3, n_nodes);
        csr_scatter_kernel<<<egrid, 256, 0, stream>>>(ei, flag3, offs3, cursor3, csr3, n_edges, n_nodes);
        const int n_groups = (n_nodes + 3) / 4;
        const int fgrid = n_groups < 4096 ? n_groups : 4096;
        sage_fused_l1_kernel<<<fgrid, 256, 0, stream>>>(x, offs3, degc3, dinv3, csr3,
                                                        W1l, b1, W1r, hf, n_nodes);
        sage_fused_l2_kernel<<<fgrid, 256, 0, stream>>>(hf, offs3, degc3, dinv3, csr3,
                                                        W2l, b2, W2r, out, n_nodes);
    }
}

// Round 7
// 306.443 us; speedup vs baseline: 1.2731x; 1.2731x over previous
//
#include <hip/hip_runtime.h>
#include <hip/hip_bf16.h>

#define FEAT 64

typedef __bf16 bf16x8 __attribute__((ext_vector_type(8)));
typedef __bf16 bf16x4 __attribute__((ext_vector_type(4)));
typedef float  f32x4  __attribute__((ext_vector_type(4)));

// ---------------------------------------------------------------------------
// Zero kernels (hipMemsetAsync may execute at capture time, not as a graph
// node -> poisoned on replay; learned in R2).
// ---------------------------------------------------------------------------
__global__ __launch_bounds__(256)
void zero1_kernel(int* __restrict__ a, int n) {
    int i = blockIdx.x * 256 + threadIdx.x;
    if (i < n) a[i] = 0;
}

__global__ __launch_bounds__(256)
void zero2_kernel(int* __restrict__ a, int* __restrict__ b, int n) {
    int i = blockIdx.x * 256 + threadIdx.x;
    if (i < n) { a[i] = 0; b[i] = 0; }
}

// ---------------------------------------------------------------------------
// int64-vs-int32 edge_index sniffer (flag=1 if int64).
// ---------------------------------------------------------------------------
__global__ void detect_idx_kernel(const unsigned* __restrict__ w, int* __restrict__ flag) {
    __shared__ int any_nz;
    if (threadIdx.x == 0) any_nz = 0;
    __syncthreads();
    if (w[2 * threadIdx.x + 1] != 0u) atomicOr(&any_nz, 1);  // first 2KB only
    __syncthreads();
    if (threadIdx.x == 0) *flag = (any_nz == 0) ? 1 : 0;
}

__device__ __forceinline__ int load_idx_clamped(const void* ei, long long i, int is64, int n_nodes) {
    int v = is64 ? (int)((const long long*)ei)[i] : ((const int*)ei)[i];
    v = v < 0 ? 0 : v;
    return v >= n_nodes ? n_nodes - 1 : v;   // identity when data is sane
}

// ---------------------------------------------------------------------------
// T1 CSR build == two-level counting sort, bucket = dst>>9 (512 nodes/bucket).
// Pack: (d&511)<<17 | s  (requires n_nodes <= 131072; guarded at launch).
// ---------------------------------------------------------------------------

// 1) exact bucket counts: LDS hist per block -> <=512 global atomics per block
__global__ __launch_bounds__(256)
void bucket_count_kernel(const void* __restrict__ ei, const int* __restrict__ flagp,
                         int* __restrict__ gcnt, int n_edges, int n_nodes) {
    __shared__ int cnt[512];
    const int t = threadIdx.x;
    cnt[t] = 0; cnt[t + 256] = 0;
    __syncthreads();
    const int is64 = *flagp;
    for (int e = blockIdx.x * 256 + t; e < n_edges; e += gridDim.x * 256) {
        int d = load_idx_clamped(ei, (long long)n_edges + e, is64, n_nodes);
        atomicAdd(&cnt[d >> 9], 1);
    }
    __syncthreads();
    if (cnt[t])       atomicAdd(&gcnt[t], cnt[t]);
    if (cnt[t + 256]) atomicAdd(&gcnt[t + 256], cnt[t + 256]);
}

// 2) exclusive scan of 512 bucket counts -> gbase (513 entries), init gcur
__global__ void bucket_scan_kernel(const int* __restrict__ gcnt, int* __restrict__ gbase,
                                   int* __restrict__ gcur, int n_edges) {
    __shared__ int sh[512];
    int t = threadIdx.x;
    int v = gcnt[t];
    sh[t] = v;
    __syncthreads();
    for (int off = 1; off < 512; off <<= 1) {
        int u = (t >= off) ? sh[t - off] : 0;
        __syncthreads();
        sh[t] += u;
        __syncthreads();
    }
    int excl = sh[t] - v;
    gbase[t] = excl;
    gcur[t]  = excl;
    if (t == 511) gbase[512] = n_edges;
}

// 3) multisplit: tile of 4096 edges staged in LDS; one global atomic per
// (tile,bucket) reserves a contiguous range; per-bucket writes from a tile
// are ~contiguous -> merge in the writing block's L2.
__global__ __launch_bounds__(256)
void multisplit_kernel(const void* __restrict__ ei, const int* __restrict__ flagp,
                       int* __restrict__ gcur, unsigned* __restrict__ B,
                       int n_edges, int n_nodes) {
    __shared__ unsigned sv[4096];
    __shared__ unsigned dv[4096];
    __shared__ int cnt[512];
    __shared__ int cur[512];
    const int t = threadIdx.x;
    const int is64 = *flagp;
    const int ntiles = (n_edges + 4095) >> 12;
    for (int tile = blockIdx.x; tile < ntiles; tile += gridDim.x) {
        cnt[t] = 0; cnt[t + 256] = 0;
        __syncthreads();
        #pragma unroll
        for (int k = 0; k < 16; ++k) {
            int i = k * 256 + t;
            int e = (tile << 12) + i;
            unsigned dmark = 0xFFFFFFFFu, s = 0;
            if (e < n_edges) {
                s     = (unsigned)load_idx_clamped(ei, e, is64, n_nodes);
                int d = load_idx_clamped(ei, (long long)n_edges + e, is64, n_nodes);
                dmark = (unsigned)d;
                atomicAdd(&cnt[d >> 9], 1);
            }
            sv[i] = s; dv[i] = dmark;
        }
        __syncthreads();
        if (cnt[t])       cur[t]       = atomicAdd(&gcur[t], cnt[t]);
        if (cnt[t + 256]) cur[t + 256] = atomicAdd(&gcur[t + 256], cnt[t + 256]);
        __syncthreads();
        #pragma unroll
        for (int k = 0; k < 16; ++k) {
            int i = k * 256 + t;
            unsigned d = dv[i];
            if (d != 0xFFFFFFFFu) {
                int pos = atomicAdd(&cur[d >> 9], 1);
                pos = pos < 0 ? 0 : (pos >= n_edges ? n_edges - 1 : pos);
                B[pos] = ((d & 511u) << 17) | sv[i];
            }
        }
        __syncthreads();
    }
}

// 4) per-bucket degree: one block per bucket, LDS hist, coalesced degc write
__global__ __launch_bounds__(256)
void bucket_degree_kernel(const unsigned* __restrict__ B, const int* __restrict__ gbase,
                          int* __restrict__ degc, int n_nodes) {
    __shared__ int cnt[512];
    const int b = blockIdx.x, t = threadIdx.x;
    cnt[t] = 0; cnt[t + 256] = 0;
    __syncthreads();
    const int lo = gbase[b], hi = gbase[b + 1];
    for (int i = lo + t; i < hi; i += 256) {
        unsigned v = B[i];
        atomicAdd(&cnt[v >> 17], 1);
    }
    __syncthreads();
    int n0 = b * 512 + t, n1 = n0 + 256;
    if (n0 < n_nodes) degc[n0] = cnt[t];
    if (n1 < n_nodes) degc[n1] = cnt[t + 256];
}

// 5) per-bucket csr build: LDS cursors seeded from offs; ALL csr writes land
// in this bucket's ~32KB contiguous range from ONE CU -> single-XCD L2 merge.
__global__ __launch_bounds__(256)
void csr_build_kernel(const unsigned* __restrict__ B, const int* __restrict__ gbase,
                      const int* __restrict__ offs, int* __restrict__ csr,
                      int n_edges, int n_nodes) {
    __shared__ int cur[512];
    const int b = blockIdx.x, t = threadIdx.x;
    int n0 = b * 512 + t, n1 = n0 + 256;
    cur[t]       = (n0 < n_nodes) ? offs[n0] : 0;
    cur[t + 256] = (n1 < n_nodes) ? offs[n1] : 0;
    __syncthreads();
    const int lo = gbase[b], hi = gbase[b + 1];
    for (int i = lo + t; i < hi; i += 256) {
        unsigned v = B[i];
        int pos = atomicAdd(&cur[v >> 17], 1);
        pos = pos < 0 ? 0 : (pos >= n_edges ? n_edges - 1 : pos);
        csr[pos] = (int)(v & 0x1FFFFu);
    }
}

// ---------------------------------------------------------------------------
// Scans (shared by all paths)
// ---------------------------------------------------------------------------
__global__ __launch_bounds__(256)
void scan_partial_kernel(const int* __restrict__ degc, int* __restrict__ part, int n_nodes) {
    __shared__ int sh[256];
    int i = blockIdx.x * 256 + threadIdx.x;
    sh[threadIdx.x] = (i < n_nodes) ? degc[i] : 0;
    __syncthreads();
    for (int off = 128; off > 0; off >>= 1) {
        if (threadIdx.x < off) sh[threadIdx.x] += sh[threadIdx.x + off];
        __syncthreads();
    }
    if (threadIdx.x == 0) part[blockIdx.x] = sh[0];
}

__global__ void scan_top_kernel(int* __restrict__ part, int nparts) {
    __shared__ int sh[512];
    int t = threadIdx.x;
    int v = (t < nparts) ? part[t] : 0;
    sh[t] = v;
    __syncthreads();
    for (int off = 1; off < 512; off <<= 1) {
        int u = (t >= off) ? sh[t - off] : 0;
        __syncthreads();
        sh[t] += u;
        __syncthreads();
    }
    if (t < nparts) part[t] = sh[t] - v;   // exclusive
}

__global__ __launch_bounds__(256)
void scan_final_kernel(const int* __restrict__ degc, const int* __restrict__ part,
                       int* __restrict__ offs, float* __restrict__ deg_inv, int n_nodes) {
    __shared__ int sh[256];
    int t = threadIdx.x;
    int i = blockIdx.x * 256 + t;
    int v = (i < n_nodes) ? degc[i] : 0;
    sh[t] = v;
    __syncthreads();
    for (int off = 1; off < 256; off <<= 1) {
        int u = (t >= off) ? sh[t - off] : 0;
        __syncthreads();
        sh[t] += u;
        __syncthreads();
    }
    if (i < n_nodes) {
        offs[i]    = sh[t] - v + part[blockIdx.x];
        deg_inv[i] = 1.0f / fmaxf((float)v, 1.0f);
    }
}

// ---------------------------------------------------------------------------
// T3 path (R4, proven): global-atomic hist + cursor scatter.
// ---------------------------------------------------------------------------
__global__ __launch_bounds__(256)
void hist_kernel(const void* __restrict__ ei, const int* __restrict__ flagp,
                 int* __restrict__ degc, int n_edges, int n_nodes) {
    int e = blockIdx.x * 256 + threadIdx.x;
    if (e >= n_edges) return;
    int d = load_idx_clamped(ei, (long long)n_edges + e, *flagp, n_nodes);
    atomicAdd(&degc[d], 1);
}

__global__ __launch_bounds__(256)
void csr_scatter_kernel(const void* __restrict__ ei, const int* __restrict__ flagp,
                        const int* __restrict__ offs, int* __restrict__ cursor,
                        int* __restrict__ csr, int n_edges, int n_nodes) {
    int e = blockIdx.x * 256 + threadIdx.x;
    if (e >= n_edges) return;
    int is64 = *flagp;
    int s = load_idx_clamped(ei, e, is64, n_nodes);
    int d = load_idx_clamped(ei, (long long)n_edges + e, is64, n_nodes);
    int pos = offs[d] + atomicAdd(&cursor[d], 1);
    pos = pos < 0 ? 0 : (pos >= n_edges ? n_edges - 1 : pos);
    csr[pos] = s;
}

// ---------------------------------------------------------------------------
// Casts
// ---------------------------------------------------------------------------
__global__ __launch_bounds__(256)
void cast_w_kernel(const float* __restrict__ a, const float* __restrict__ b,
                   const float* __restrict__ c, const float* __restrict__ d,
                   __bf16* __restrict__ o) {
    int i = blockIdx.x * 256 + threadIdx.x;
    if (i < FEAT * FEAT) {
        o[i]         = (__bf16)a[i];
        o[4096 + i]  = (__bf16)b[i];
        o[8192 + i]  = (__bf16)c[i];
        o[12288 + i] = (__bf16)d[i];
    }
}

__global__ __launch_bounds__(256)
void cast_x_kernel(const float* __restrict__ x, __bf16* __restrict__ xb, int n4) {
    int i = blockIdx.x * 256 + threadIdx.x;
    if (i < n4) {
        float4 v = ((const float4*)x)[i];
        bf16x4 o;
        o.x = (__bf16)v.x; o.y = (__bf16)v.y; o.z = (__bf16)v.z; o.w = (__bf16)v.w;
        ((bf16x4*)xb)[i] = o;
    }
}

// ---------------------------------------------------------------------------
// Gather kernels: wave per node, no LDS; 4 groups of 16 lanes = 4 independent
// chains; butterfly merge; group 0 stores mean row bf16x4.
// ---------------------------------------------------------------------------
__global__ __launch_bounds__(256)
void gather_f32_kernel(const float* __restrict__ xin, const int* __restrict__ offs,
                       const int* __restrict__ degc, const float* __restrict__ dinv,
                       const int* __restrict__ csr, __bf16* __restrict__ agg,
                       int n_nodes) {
    const int t = threadIdx.x, lane = t & 63, g = lane >> 4, u = lane & 15;
    const int gw = blockIdx.x * 4 + (t >> 6), nw = gridDim.x * 4;
    for (int n = gw; n < n_nodes; n += nw) {
        int rs = offs[n], cnt = degc[n];
        float a0 = 0.f, a1 = 0.f, a2 = 0.f, a3 = 0.f;
        for (int c = 0; c < cnt; c += 64) {
            int chunk = min(64, cnt - c);
            int myid = (lane < chunk) ? csr[rs + c + lane] : 0;
            myid = myid < 0 ? 0 : (myid >= n_nodes ? n_nodes - 1 : myid);
            for (int q = 0; q < chunk; q += 4) {
                int qq = q + g;
                int s = __shfl(myid, qq);
                if (qq < chunk) {
                    const float4 v = ((const float4*)xin)[(size_t)s * 16 + u];
                    a0 += v.x; a1 += v.y; a2 += v.z; a3 += v.w;
                }
            }
        }
        a0 += __shfl_xor(a0, 16); a1 += __shfl_xor(a1, 16);
        a2 += __shfl_xor(a2, 16); a3 += __shfl_xor(a3, 16);
        a0 += __shfl_xor(a0, 32); a1 += __shfl_xor(a1, 32);
        a2 += __shfl_xor(a2, 32); a3 += __shfl_xor(a3, 32);
        if (g == 0) {
            float di = dinv[n];
            bf16x4 o;
            o.x = (__bf16)(a0 * di); o.y = (__bf16)(a1 * di);
            o.z = (__bf16)(a2 * di); o.w = (__bf16)(a3 * di);
            ((bf16x4*)agg)[(size_t)n * 16 + u] = o;
        }
    }
}

__global__ __launch_bounds__(256)
void gather_bf16_kernel(const __bf16* __restrict__ hin, const int* __restrict__ offs,
                        const int* __restrict__ degc, const float* __restrict__ dinv,
                        const int* __restrict__ csr, __bf16* __restrict__ agg,
                        int n_nodes) {
    const int t = threadIdx.x, lane = t & 63, g = lane >> 4, u = lane & 15;
    const int gw = blockIdx.x * 4 + (t >> 6), nw = gridDim.x * 4;
    for (int n = gw; n < n_nodes; n += nw) {
        int rs = offs[n], cnt = degc[n];
        float a0 = 0.f, a1 = 0.f, a2 = 0.f, a3 = 0.f;
        for (int c = 0; c < cnt; c += 64) {
            int chunk = min(64, cnt - c);
            int myid = (lane < chunk) ? csr[rs + c + lane] : 0;
            myid = myid < 0 ? 0 : (myid >= n_nodes ? n_nodes - 1 : myid);
            for (int q = 0; q < chunk; q += 4) {
                int qq = q + g;
                int s = __shfl(myid, qq);
                if (qq < chunk) {
                    const bf16x4 v = ((const bf16x4*)hin)[(size_t)s * 16 + u];
                    a0 += (float)v.x; a1 += (float)v.y; a2 += (float)v.z; a3 += (float)v.w;
                }
            }
        }
        a0 += __shfl_xor(a0, 16); a1 += __shfl_xor(a1, 16);
        a2 += __shfl_xor(a2, 16); a3 += __shfl_xor(a3, 16);
        a0 += __shfl_xor(a0, 32); a1 += __shfl_xor(a1, 32);
        a2 += __shfl_xor(a2, 32); a3 += __shfl_xor(a3, 32);
        if (g == 0) {
            float di = dinv[n];
            bf16x4 o;
            o.x = (__bf16)(a0 * di); o.y = (__bf16)(a1 * di);
            o.z = (__bf16)(a2 * di); o.w = (__bf16)(a3 * di);
            ((bf16x4*)agg)[(size_t)n * 16 + u] = o;
        }
    }
}

// ---------------------------------------------------------------------------
// MFMA GEMMs (16x16x32 bf16; verified fragment layouts).
// ---------------------------------------------------------------------------
__global__ __launch_bounds__(256)
void gemm_l1b_kernel(const __bf16* __restrict__ Ag, const __bf16* __restrict__ xb,
                     const __bf16* __restrict__ Bl, const __bf16* __restrict__ Br,
                     const float* __restrict__ bias,
                     __bf16* __restrict__ hout, int n_nodes) {
    const int t = threadIdx.x, lane = t & 63;
    const int quad = lane >> 4, r16 = lane & 15;
    bf16x8 bl[2][4], br[2][4];
    #pragma unroll
    for (int ks = 0; ks < 2; ++ks)
        #pragma unroll
        for (int ct = 0; ct < 4; ++ct) {
            int f = ct * 16 + r16, k = ks * 32 + quad * 8;
            bl[ks][ct] = *(const bf16x8*)(Bl + f * 64 + k);
            br[ks][ct] = *(const bf16x8*)(Br + f * 64 + k);
        }
    const int m0 = (blockIdx.x * 4 + (t >> 6)) * 16;
    if (m0 >= n_nodes) return;
    int mrow = m0 + r16; if (mrow >= n_nodes) mrow = n_nodes - 1;
    bf16x8 ag[2], ax[2];
    #pragma unroll
    for (int ks = 0; ks < 2; ++ks) {
        ag[ks] = *(const bf16x8*)(Ag + (size_t)mrow * 64 + ks * 32 + quad * 8);
        ax[ks] = *(const bf16x8*)(xb + (size_t)mrow * 64 + ks * 32 + quad * 8);
    }
    #pragma unroll
    for (int ct = 0; ct < 4; ++ct) {
        f32x4 acc = {0.f, 0.f, 0.f, 0.f};
        acc = __builtin_amdgcn_mfma_f32_16x16x32_bf16(ag[0], bl[0][ct], acc, 0, 0, 0);
        acc = __builtin_amdgcn_mfma_f32_16x16x32_bf16(ag[1], bl[1][ct], acc, 0, 0, 0);
        acc = __builtin_amdgcn_mfma_f32_16x16x32_bf16(ax[0], br[0][ct], acc, 0, 0, 0);
        acc = __builtin_amdgcn_mfma_f32_16x16x32_bf16(ax[1], br[1][ct], acc, 0, 0, 0);
        int col = ct * 16 + r16;
        float bv = bias[col];
        #pragma unroll
        for (int rg = 0; rg < 4; ++rg) {
            int n = m0 + quad * 4 + rg;
            if (n < n_nodes) {
                float o = acc[rg] + bv;
                hout[(size_t)n * 64 + col] = (__bf16)fmaxf(o, 0.f);
            }
        }
    }
}

__global__ __launch_bounds__(256)
void gemm_l1_kernel(const __bf16* __restrict__ Ag, const float* __restrict__ xin,
                    const __bf16* __restrict__ Bl, const __bf16* __restrict__ Br,
                    const float* __restrict__ bias,
                    __bf16* __restrict__ hout, int n_nodes) {
    const int t = threadIdx.x, lane = t & 63;
    const int quad = lane >> 4, r16 = lane & 15;
    bf16x8 bl[2][4], br[2][4];
    #pragma unroll
    for (int ks = 0; ks < 2; ++ks)
        #pragma unroll
        for (int ct = 0; ct < 4; ++ct) {
            int f = ct * 16 + r16, k = ks * 32 + quad * 8;
            bl[ks][ct] = *(const bf16x8*)(Bl + f * 64 + k);
            br[ks][ct] = *(const bf16x8*)(Br + f * 64 + k);
        }
    const int m0 = (blockIdx.x * 4 + (t >> 6)) * 16;
    if (m0 >= n_nodes) return;
    int mrow = m0 + r16; if (mrow >= n_nodes) mrow = n_nodes - 1;
    bf16x8 ag[2], ax[2];
    #pragma unroll
    for (int ks = 0; ks < 2; ++ks) {
        ag[ks] = *(const bf16x8*)(Ag + (size_t)mrow * 64 + ks * 32 + quad * 8);
        const float* xr = xin + (size_t)mrow * 64 + ks * 32 + quad * 8;
        float4 p = *(const float4*)xr;
        float4 q = *(const float4*)(xr + 4);
        union { bf16x8 v; __bf16 e[8]; } U;
        U.e[0] = (__bf16)p.x; U.e[1] = (__bf16)p.y; U.e[2] = (__bf16)p.z; U.e[3] = (__bf16)p.w;
        U.e[4] = (__bf16)q.x; U.e[5] = (__bf16)q.y; U.e[6] = (__bf16)q.z; U.e[7] = (__bf16)q.w;
        ax[ks] = U.v;
    }
    #pragma unroll
    for (int ct = 0; ct < 4; ++ct) {
        f32x4 acc = {0.f, 0.f, 0.f, 0.f};
        acc = __builtin_amdgcn_mfma_f32_16x16x32_bf16(ag[0], bl[0][ct], acc, 0, 0, 0);
        acc = __builtin_amdgcn_mfma_f32_16x16x32_bf16(ag[1], bl[1][ct], acc, 0, 0, 0);
        acc = __builtin_amdgcn_mfma_f32_16x16x32_bf16(ax[0], br[0][ct], acc, 0, 0, 0);
        acc = __builtin_amdgcn_mfma_f32_16x16x32_bf16(ax[1], br[1][ct], acc, 0, 0, 0);
        int col = ct * 16 + r16;
        float bv = bias[col];
        #pragma unroll
        for (int rg = 0; rg < 4; ++rg) {
            int n = m0 + quad * 4 + rg;
            if (n < n_nodes) {
                float o = acc[rg] + bv;
                hout[(size_t)n * 64 + col] = (__bf16)fmaxf(o, 0.f);
            }
        }
    }
}

__global__ __launch_bounds__(256)
void gemm_l2_kernel(const __bf16* __restrict__ Ag, const __bf16* __restrict__ Ah,
                    const __bf16* __restrict__ Bl, const __bf16* __restrict__ Br,
                    const float* __restrict__ bias,
                    float* __restrict__ out, int n_nodes) {
    const int t = threadIdx.x, lane = t & 63;
    const int quad = lane >> 4, r16 = lane & 15;
    bf16x8 bl[2][4], br[2][4];
    #pragma unroll
    for (int ks = 0; ks < 2; ++ks)
        #pragma unroll
        for (int ct = 0; ct < 4; ++ct) {
            int f = ct * 16 + r16, k = ks * 32 + quad * 8;
            bl[ks][ct] = *(const bf16x8*)(Bl + f * 64 + k);
            br[ks][ct] = *(const bf16x8*)(Br + f * 64 + k);
        }
    const int m0 = (blockIdx.x * 4 + (t >> 6)) * 16;
    if (m0 >= n_nodes) return;
    int mrow = m0 + r16; if (mrow >= n_nodes) mrow = n_nodes - 1;
    bf16x8 ag[2], ah[2];
    #pragma unroll
    for (int ks = 0; ks < 2; ++ks) {
        ag[ks] = *(const bf16x8*)(Ag + (size_t)mrow * 64 + ks * 32 + quad * 8);
        ah[ks] = *(const bf16x8*)(Ah + (size_t)mrow * 64 + ks * 32 + quad * 8);
    }
    #pragma unroll
    for (int ct = 0; ct < 4; ++ct) {
        f32x4 acc = {0.f, 0.f, 0.f, 0.f};
        acc = __builtin_amdgcn_mfma_f32_16x16x32_bf16(ag[0], bl[0][ct], acc, 0, 0, 0);
        acc = __builtin_amdgcn_mfma_f32_16x16x32_bf16(ag[1], bl[1][ct], acc, 0, 0, 0);
        acc = __builtin_amdgcn_mfma_f32_16x16x32_bf16(ah[0], br[0][ct], acc, 0, 0, 0);
        acc = __builtin_amdgcn_mfma_f32_16x16x32_bf16(ah[1], br[1][ct], acc, 0, 0, 0);
        int col = ct * 16 + r16;
        float bv = bias[col];
        #pragma unroll
        for (int rg = 0; rg < 4; ++rg) {
            int n = m0 + quad * 4 + rg;
            if (n < n_nodes) out[(size_t)n * 64 + col] = acc[rg] + bv;
        }
    }
}

// ---------------------------------------------------------------------------
// T4 fallback (R3): fused LDS kernels.
// ---------------------------------------------------------------------------
__global__ __launch_bounds__(256)
void sage_fused_l1_kernel(const float* __restrict__ xin,
                          const int* __restrict__ offs, const int* __restrict__ degc,
                          const float* __restrict__ deg_inv, const int* __restrict__ csr,
                          const float* __restrict__ Wl, const float* __restrict__ bias,
                          const float* __restrict__ Wr,
                          __bf16* __restrict__ hout, int n_nodes) {
    __shared__ float WlT[FEAT * 65], WrT[FEAT * 65], bsh[FEAT];
    __shared__ float aggS[4][FEAT], selfS[4][FEAT];
    const int t = threadIdx.x;
    #pragma unroll
    for (int p = 0; p < 16; ++p) {
        int i = t + p * 256, j = i >> 6, k = i & 63;
        WlT[k * 65 + j] = Wl[i];
        WrT[k * 65 + j] = Wr[i];
    }
    if (t < FEAT) bsh[t] = bias[t];
    __syncthreads();
    const int w = t >> 6, f = t & 63;
    const int n_groups = (n_nodes + 3) >> 2;
    for (int g = blockIdx.x; g < n_groups; g += gridDim.x) {
        int n = g * 4 + w;
        bool act = (n < n_nodes);
        if (act) {
            int rs = offs[n], cnt = degc[n];
            float acc = 0.f;
            for (int c = 0; c < cnt; c += 64) {
                int chunk = min(64, cnt - c);
                int myid = (f < chunk) ? csr[rs + c + f] : 0;
                #pragma unroll 4
                for (int q = 0; q < chunk; ++q) {
                    int s = __shfl(myid, q);
                    acc += xin[(long long)s * FEAT + f];
                }
            }
            aggS[w][f]  = acc * deg_inv[n];
            selfS[w][f] = xin[(long long)n * FEAT + f];
        }
        __syncthreads();
        if (act) {
            float o = bsh[f];
            #pragma unroll
            for (int k = 0; k < FEAT; ++k) {
                o = fmaf(aggS[w][k],  WlT[k * 65 + f], o);
                o = fmaf(selfS[w][k], WrT[k * 65 + f], o);
            }
            o = fmaxf(o, 0.f);
            hout[(long long)n * FEAT + f] = (__bf16)o;
        }
        __syncthreads();
    }
}

__global__ __launch_bounds__(256)
void sage_fused_l2_kernel(const __bf16* __restrict__ hin,
                          const int* __restrict__ offs, const int* __restrict__ degc,
                          const float* __restrict__ deg_inv, const int* __restrict__ csr,
                          const float* __restrict__ Wl, const float* __restrict__ bias,
                          const float* __restrict__ Wr,
                          float* __restrict__ out, int n_nodes) {
    __shared__ float WlT[FEAT * 65], WrT[FEAT * 65], bsh[FEAT];
    __shared__ float aggS[4][FEAT], selfS[4][FEAT];
    const int t = threadIdx.x;
    #pragma unroll
    for (int p = 0; p < 16; ++p) {
        int i = t + p * 256, j = i >> 6, k = i & 63;
        WlT[k * 65 + j] = Wl[i];
        WrT[k * 65 + j] = Wr[i];
    }
    if (t < FEAT) bsh[t] = bias[t];
    __syncthreads();
    const int w = t >> 6, f = t & 63;
    const int n_groups = (n_nodes + 3) >> 2;
    for (int g = blockIdx.x; g < n_groups; g += gridDim.x) {
        int n = g * 4 + w;
        bool act = (n < n_nodes);
        if (act) {
            int rs = offs[n], cnt = degc[n];
            float acc = 0.f;
            for (int c = 0; c < cnt; c += 64) {
                int chunk = min(64, cnt - c);
                int myid = (f < chunk) ? csr[rs + c + f] : 0;
                #pragma unroll 4
                for (int q = 0; q < chunk; ++q) {
                    int s = __shfl(myid, q);
                    acc += (float)hin[(long long)s * FEAT + f];
                }
            }
            aggS[w][f]  = acc * deg_inv[n];
            selfS[w][f] = (float)hin[(long long)n * FEAT + f];
        }
        __syncthreads();
        if (act) {
            float o = bsh[f];
            #pragma unroll
            for (int k = 0; k < FEAT; ++k) {
                o = fmaf(aggS[w][k],  WlT[k * 65 + f], o);
                o = fmaf(selfS[w][k], WrT[k * 65 + f], o);
            }
            out[(long long)n * FEAT + f] = o;
        }
        __syncthreads();
    }
}

// ---------------------------------------------------------------------------
// Launch
// ---------------------------------------------------------------------------
extern "C" void kernel_launch(void* const* d_in, const int* in_sizes, int n_in,
                              void* d_out, int out_size, void* d_ws, size_t ws_size,
                              hipStream_t stream) {
    const float* x   = (const float*)d_in[0];
    const void*  ei  = d_in[1];
    const float* W1l = (const float*)d_in[2];
    const float* b1  = (const float*)d_in[3];
    const float* W1r = (const float*)d_in[4];
    const float* W2l = (const float*)d_in[5];
    const float* b2  = (const float*)d_in[6];
    const float* W2r = (const float*)d_in[7];
    float* out = (float*)d_out;

    const int n_nodes = in_sizes[0] / FEAT;
    const int n_edges = in_sizes[1] / 2;
    const int nparts  = (n_nodes + 255) / 256;     // <= 512
    const int egrid   = (n_edges + 255) / 256;
    const int NB      = (n_nodes + 511) >> 9;      // buckets of 512 nodes

    char* ws = (char*)d_ws;
    auto al = [](size_t v) { return (v + 255) & ~(size_t)255; };

    // ---- T1 layout (two-level counting sort; slightly smaller than R5's) ----
    size_t o = 0;
    int*      flag  = (int*)(ws + o);      o += 256;
    int*      degc  = (int*)(ws + o);      o += al((size_t)n_nodes * 4);
    float*    dinv  = (float*)(ws + o);    o += al((size_t)n_nodes * 4);
    int*      offs  = (int*)(ws + o);      o += al((size_t)n_nodes * 4);
    int*      part  = (int*)(ws + o);      o += al(2048);
    int*      gcnt  = (int*)(ws + o);      o += al(512 * 4);
    int*      gbase = (int*)(ws + o);      o += al(513 * 4);
    int*      gcur  = (int*)(ws + o);      o += al(512 * 4);
    unsigned* B     = (unsigned*)(ws + o); o += al((size_t)n_edges * 4);
    int*      csr   = (int*)(ws + o);      o += al((size_t)n_edges * 4);
    __bf16*   xb    = (__bf16*)(ws + o);   o += al((size_t)n_nodes * FEAT * 2);
    __bf16*   wb    = (__bf16*)(ws + o);   o += al((size_t)4 * FEAT * FEAT * 2);
    __bf16*   agg   = (__bf16*)(ws + o);   o += al((size_t)n_nodes * FEAT * 2);
    __bf16*   h     = (__bf16*)(ws + o);   o += al((size_t)n_nodes * FEAT * 2);
    const size_t needT1 = o;

    // ---- T3 layout (R4, proven) ----
    size_t o3 = 0;
    int*    flag3   = (int*)(ws + o3);    o3 += 256;
    int*    degc3   = (int*)(ws + o3);    o3 += al((size_t)n_nodes * 4);
    float*  dinv3   = (float*)(ws + o3);  o3 += al((size_t)n_nodes * 4);
    int*    offs3   = (int*)(ws + o3);    o3 += al((size_t)n_nodes * 4);
    int*    cursor3 = (int*)(ws + o3);    o3 += al((size_t)n_nodes * 4);
    int*    part3   = (int*)(ws + o3);    o3 += al(2048);
    int*    csr3    = (int*)(ws + o3);    o3 += al((size_t)n_edges * 4);
    const size_t commonEnd3 = o3;
    __bf16* wb3  = (__bf16*)(ws + o3);    o3 += al((size_t)4 * FEAT * FEAT * 2);
    __bf16* agg3 = (__bf16*)(ws + o3);    o3 += al((size_t)n_nodes * FEAT * 2);
    __bf16* h3   = (__bf16*)(ws + o3);    o3 += al((size_t)n_nodes * FEAT * 2);
    const size_t needT3 = o3;

    const int n4 = n_nodes * FEAT / 4;
    const int mgrid = (n_nodes + 63) / 64;
    const int ggrid = 2048;
    const int ntiles = (n_edges + 4095) >> 12;

    if (ws_size >= needT1 && n_nodes <= 131072) {
        zero1_kernel<<<2, 256, 0, stream>>>(gcnt, 512);
        detect_idx_kernel<<<1, 256, 0, stream>>>((const unsigned*)ei, flag);
        bucket_count_kernel<<<512, 256, 0, stream>>>(ei, flag, gcnt, n_edges, n_nodes);
        bucket_scan_kernel<<<1, 512, 0, stream>>>(gcnt, gbase, gcur, n_edges);
        multisplit_kernel<<<ntiles, 256, 0, stream>>>(ei, flag, gcur, B, n_edges, n_nodes);
        bucket_degree_kernel<<<NB, 256, 0, stream>>>(B, gbase, degc, n_nodes);
        scan_partial_kernel<<<nparts, 256, 0, stream>>>(degc, part, n_nodes);
        scan_top_kernel<<<1, 512, 0, stream>>>(part, nparts);
        scan_final_kernel<<<nparts, 256, 0, stream>>>(degc, part, offs, dinv, n_nodes);
        cast_x_kernel<<<(n4 + 255) / 256, 256, 0, stream>>>(x, xb, n4);
        cast_w_kernel<<<16, 256, 0, stream>>>(W1l, W1r, W2l, W2r, wb);
        csr_build_kernel<<<NB, 256, 0, stream>>>(B, gbase, offs, csr, n_edges, n_nodes);
        gather_bf16_kernel<<<ggrid, 256, 0, stream>>>(xb, offs, degc, dinv, csr, agg, n_nodes);
        gemm_l1b_kernel<<<mgrid, 256, 0, stream>>>(agg, xb, wb, wb + 4096, b1, h, n_nodes);
        gather_bf16_kernel<<<ggrid, 256, 0, stream>>>(h, offs, degc, dinv, csr, agg, n_nodes);
        gemm_l2_kernel<<<mgrid, 256, 0, stream>>>(agg, h, wb + 8192, wb + 12288, b2, out, n_nodes);
    } else if (ws_size >= needT3) {
        zero2_kernel<<<nparts, 256, 0, stream>>>(degc3, cursor3, n_nodes);
        detect_idx_kernel<<<1, 256, 0, stream>>>((const unsigned*)ei, flag3);
        hist_kernel<<<egrid, 256, 0, stream>>>(ei, flag3, degc3, n_edges, n_nodes);
        scan_partial_kernel<<<nparts, 256, 0, stream>>>(degc3, part3, n_nodes);
        scan_top_kernel<<<1, 512, 0, stream>>>(part3, nparts);
        scan_final_kernel<<<nparts, 256, 0, stream>>>(degc3, part3, offs3, dinv3, n_nodes);
        csr_scatter_kernel<<<egrid, 256, 0, stream>>>(ei, flag3, offs3, cursor3, csr3, n_edges, n_nodes);
        cast_w_kernel<<<16, 256, 0, stream>>>(W1l, W1r, W2l, W2r, wb3);
        gather_f32_kernel<<<ggrid, 256, 0, stream>>>(x, offs3, degc3, dinv3, csr3, agg3, n_nodes);
        gemm_l1_kernel<<<mgrid, 256, 0, stream>>>(agg3, x, wb3, wb3 + 4096, b1, h3, n_nodes);
        gather_bf16_kernel<<<ggrid, 256, 0, stream>>>(h3, offs3, degc3, dinv3, csr3, agg3, n_nodes);
        gemm_l2_kernel<<<mgrid, 256, 0, stream>>>(agg3, h3, wb3 + 8192, wb3 + 12288, b2, out, n_nodes);
    } else {
        __bf16* hf = (__bf16*)(ws + commonEnd3);
        zero2_kernel<<<nparts, 256, 0, stream>>>(degc3, cursor3, n_nodes);
        detect_idx_kernel<<<1, 256, 0, stream>>>((const unsigned*)ei, flag3);
        hist_kernel<<<egrid, 256, 0, stream>>>(ei, flag3, degc3, n_edges, n_nodes);
        scan_partial_kernel<<<nparts, 256, 0, stream>>>(degc3, part3, n_nodes);
        scan_top_kernel<<<1, 512, 0, stream>>>(part3, nparts);
        scan_final_kernel<<<nparts, 256, 0, stream>>>(degc3, part3, offs3, dinv3, n_nodes);
        csr_scatter_kernel<<<egrid, 256, 0, stream>>>(ei, flag3, offs3, cursor3, csr3, n_edges, n_nodes);
        const int n_groups = (n_nodes + 3) / 4;
        const int fgrid = n_groups < 4096 ? n_groups : 4096;
        sage_fused_l1_kernel<<<fgrid, 256, 0, stream>>>(x, offs3, degc3, dinv3, csr3,
                                                        W1l, b1, W1r, hf, n_nodes);
        sage_fused_l2_kernel<<<fgrid, 256, 0, stream>>>(hf, offs3, degc3, dinv3, csr3,
                                                        W2l, b2, W2r, out, n_nodes);
    }
}

// Round 8
// 281.626 us; speedup vs baseline: 1.3853x; 1.0881x over previous
//
#include <hip/hip_runtime.h>
#include <hip/hip_bf16.h>

#define FEAT 64

typedef __bf16 bf16x8 __attribute__((ext_vector_type(8)));
typedef __bf16 bf16x4 __attribute__((ext_vector_type(4)));
typedef float  f32x4  __attribute__((ext_vector_type(4)));

// ---------------------------------------------------------------------------
// Zero kernels (hipMemsetAsync may execute at capture time, not as a graph
// node -> poisoned on replay; learned in R2).
// ---------------------------------------------------------------------------
__global__ __launch_bounds__(256)
void zero1_kernel(int* __restrict__ a, int n) {
    int i = blockIdx.x * 256 + threadIdx.x;
    if (i < n) a[i] = 0;
}

__global__ __launch_bounds__(256)
void zero2_kernel(int* __restrict__ a, int* __restrict__ b, int n) {
    int i = blockIdx.x * 256 + threadIdx.x;
    if (i < n) { a[i] = 0; b[i] = 0; }
}

// ---------------------------------------------------------------------------
// int64-vs-int32 edge_index sniffer (flag=1 if int64).
// ---------------------------------------------------------------------------
__global__ void detect_idx_kernel(const unsigned* __restrict__ w, int* __restrict__ flag) {
    __shared__ int any_nz;
    if (threadIdx.x == 0) any_nz = 0;
    __syncthreads();
    if (w[2 * threadIdx.x + 1] != 0u) atomicOr(&any_nz, 1);  // first 2KB only
    __syncthreads();
    if (threadIdx.x == 0) *flag = (any_nz == 0) ? 1 : 0;
}

__device__ __forceinline__ int load_idx_clamped(const void* ei, long long i, int is64, int n_nodes) {
    int v = is64 ? (int)((const long long*)ei)[i] : ((const int*)ei)[i];
    v = v < 0 ? 0 : v;
    return v >= n_nodes ? n_nodes - 1 : v;   // identity when data is sane
}

// ---------------------------------------------------------------------------
// T1 CSR build == two-level counting sort, bucket = dst>>9 (512 nodes/bucket).
// Pack: (d&511)<<17 | s  (requires n_nodes <= 131072; guarded at launch).
// ---------------------------------------------------------------------------

// 1) exact bucket counts: LDS hist per block -> <=512 global atomics per block
__global__ __launch_bounds__(256)
void bucket_count_kernel(const void* __restrict__ ei, const int* __restrict__ flagp,
                         int* __restrict__ gcnt, int n_edges, int n_nodes) {
    __shared__ int cnt[512];
    const int t = threadIdx.x;
    cnt[t] = 0; cnt[t + 256] = 0;
    __syncthreads();
    const int is64 = *flagp;
    for (int e = blockIdx.x * 256 + t; e < n_edges; e += gridDim.x * 256) {
        int d = load_idx_clamped(ei, (long long)n_edges + e, is64, n_nodes);
        atomicAdd(&cnt[d >> 9], 1);
    }
    __syncthreads();
    if (cnt[t])       atomicAdd(&gcnt[t], cnt[t]);
    if (cnt[t + 256]) atomicAdd(&gcnt[t + 256], cnt[t + 256]);
}

// 2) exclusive scan of 512 bucket counts -> gbase (513 entries), init gcur
__global__ void bucket_scan_kernel(const int* __restrict__ gcnt, int* __restrict__ gbase,
                                   int* __restrict__ gcur, int n_edges) {
    __shared__ int sh[512];
    int t = threadIdx.x;
    int v = gcnt[t];
    sh[t] = v;
    __syncthreads();
    for (int off = 1; off < 512; off <<= 1) {
        int u = (t >= off) ? sh[t - off] : 0;
        __syncthreads();
        sh[t] += u;
        __syncthreads();
    }
    int excl = sh[t] - v;
    gbase[t] = excl;
    gcur[t]  = excl;
    if (t == 511) gbase[512] = n_edges;
}

// 3) multisplit: tile of 4096 edges staged in LDS; one global atomic per
// (tile,bucket) reserves a contiguous range; per-bucket writes from a tile
// are ~contiguous -> merge in the writing block's L2.
__global__ __launch_bounds__(256)
void multisplit_kernel(const void* __restrict__ ei, const int* __restrict__ flagp,
                       int* __restrict__ gcur, unsigned* __restrict__ B,
                       int n_edges, int n_nodes) {
    __shared__ unsigned sv[4096];
    __shared__ unsigned dv[4096];
    __shared__ int cnt[512];
    __shared__ int cur[512];
    const int t = threadIdx.x;
    const int is64 = *flagp;
    const int ntiles = (n_edges + 4095) >> 12;
    for (int tile = blockIdx.x; tile < ntiles; tile += gridDim.x) {
        cnt[t] = 0; cnt[t + 256] = 0;
        __syncthreads();
        #pragma unroll
        for (int k = 0; k < 16; ++k) {
            int i = k * 256 + t;
            int e = (tile << 12) + i;
            unsigned dmark = 0xFFFFFFFFu, s = 0;
            if (e < n_edges) {
                s     = (unsigned)load_idx_clamped(ei, e, is64, n_nodes);
                int d = load_idx_clamped(ei, (long long)n_edges + e, is64, n_nodes);
                dmark = (unsigned)d;
                atomicAdd(&cnt[d >> 9], 1);
            }
            sv[i] = s; dv[i] = dmark;
        }
        __syncthreads();
        if (cnt[t])       cur[t]       = atomicAdd(&gcur[t], cnt[t]);
        if (cnt[t + 256]) cur[t + 256] = atomicAdd(&gcur[t + 256], cnt[t + 256]);
        __syncthreads();
        #pragma unroll
        for (int k = 0; k < 16; ++k) {
            int i = k * 256 + t;
            unsigned d = dv[i];
            if (d != 0xFFFFFFFFu) {
                int pos = atomicAdd(&cur[d >> 9], 1);
                pos = pos < 0 ? 0 : (pos >= n_edges ? n_edges - 1 : pos);
                B[pos] = ((d & 511u) << 17) | sv[i];
            }
        }
        __syncthreads();
    }
}

// 4) fused per-bucket: LDS hist -> LDS 512-scan -> degc/offs/dinv (coalesced)
//    -> csr placement. Global offs = gbase[bucket] + intra-bucket prefix, so
//    no global scan kernels are needed. All csr writes land in this bucket's
//    contiguous range from ONE CU -> single-XCD L2 merge (R7-proven).
__global__ __launch_bounds__(256)
void csr_build2_kernel(const unsigned* __restrict__ B, const int* __restrict__ gbase,
                       int* __restrict__ degc, int* __restrict__ offs,
                       float* __restrict__ dinv, int* __restrict__ csr,
                       int n_edges, int n_nodes) {
    __shared__ int cnt[512];
    __shared__ int scn[512];
    __shared__ int cur[512];
    const int b = blockIdx.x, t = threadIdx.x;
    cnt[t] = 0; cnt[t + 256] = 0;
    __syncthreads();
    const int lo = gbase[b], hi = gbase[b + 1];
    for (int i = lo + t; i < hi; i += 256) {
        unsigned v = B[i];
        atomicAdd(&cnt[v >> 17], 1);
    }
    __syncthreads();
    scn[t] = cnt[t]; scn[t + 256] = cnt[t + 256];
    __syncthreads();
    for (int off = 1; off < 512; off <<= 1) {
        int u0 = (t >= off) ? scn[t - off] : 0;
        int u1 = (t + 256 >= off) ? scn[t + 256 - off] : 0;
        __syncthreads();
        scn[t] += u0; scn[t + 256] += u1;
        __syncthreads();
    }
    const int base = gbase[b];
    int e0 = base + scn[t] - cnt[t];
    int e1 = base + scn[t + 256] - cnt[t + 256];
    cur[t] = e0; cur[t + 256] = e1;
    int n0 = b * 512 + t, n1 = n0 + 256;
    if (n0 < n_nodes) {
        degc[n0] = cnt[t]; offs[n0] = e0;
        dinv[n0] = 1.0f / fmaxf((float)cnt[t], 1.0f);
    }
    if (n1 < n_nodes) {
        degc[n1] = cnt[t + 256]; offs[n1] = e1;
        dinv[n1] = 1.0f / fmaxf((float)cnt[t + 256], 1.0f);
    }
    __syncthreads();
    for (int i = lo + t; i < hi; i += 256) {
        unsigned v = B[i];
        int pos = atomicAdd(&cur[v >> 17], 1);
        pos = pos < 0 ? 0 : (pos >= n_edges ? n_edges - 1 : pos);
        csr[pos] = (int)(v & 0x1FFFFu);
    }
}

// ---------------------------------------------------------------------------
// Scans (T3/T4 paths)
// ---------------------------------------------------------------------------
__global__ __launch_bounds__(256)
void scan_partial_kernel(const int* __restrict__ degc, int* __restrict__ part, int n_nodes) {
    __shared__ int sh[256];
    int i = blockIdx.x * 256 + threadIdx.x;
    sh[threadIdx.x] = (i < n_nodes) ? degc[i] : 0;
    __syncthreads();
    for (int off = 128; off > 0; off >>= 1) {
        if (threadIdx.x < off) sh[threadIdx.x] += sh[threadIdx.x + off];
        __syncthreads();
    }
    if (threadIdx.x == 0) part[blockIdx.x] = sh[0];
}

__global__ void scan_top_kernel(int* __restrict__ part, int nparts) {
    __shared__ int sh[512];
    int t = threadIdx.x;
    int v = (t < nparts) ? part[t] : 0;
    sh[t] = v;
    __syncthreads();
    for (int off = 1; off < 512; off <<= 1) {
        int u = (t >= off) ? sh[t - off] : 0;
        __syncthreads();
        sh[t] += u;
        __syncthreads();
    }
    if (t < nparts) part[t] = sh[t] - v;   // exclusive
}

__global__ __launch_bounds__(256)
void scan_final_kernel(const int* __restrict__ degc, const int* __restrict__ part,
                       int* __restrict__ offs, float* __restrict__ deg_inv, int n_nodes) {
    __shared__ int sh[256];
    int t = threadIdx.x;
    int i = blockIdx.x * 256 + t;
    int v = (i < n_nodes) ? degc[i] : 0;
    sh[t] = v;
    __syncthreads();
    for (int off = 1; off < 256; off <<= 1) {
        int u = (t >= off) ? sh[t - off] : 0;
        __syncthreads();
        sh[t] += u;
        __syncthreads();
    }
    if (i < n_nodes) {
        offs[i]    = sh[t] - v + part[blockIdx.x];
        deg_inv[i] = 1.0f / fmaxf((float)v, 1.0f);
    }
}

// ---------------------------------------------------------------------------
// T3 path (R4, proven): global-atomic hist + cursor scatter.
// ---------------------------------------------------------------------------
__global__ __launch_bounds__(256)
void hist_kernel(const void* __restrict__ ei, const int* __restrict__ flagp,
                 int* __restrict__ degc, int n_edges, int n_nodes) {
    int e = blockIdx.x * 256 + threadIdx.x;
    if (e >= n_edges) return;
    int d = load_idx_clamped(ei, (long long)n_edges + e, *flagp, n_nodes);
    atomicAdd(&degc[d], 1);
}

__global__ __launch_bounds__(256)
void csr_scatter_kernel(const void* __restrict__ ei, const int* __restrict__ flagp,
                        const int* __restrict__ offs, int* __restrict__ cursor,
                        int* __restrict__ csr, int n_edges, int n_nodes) {
    int e = blockIdx.x * 256 + threadIdx.x;
    if (e >= n_edges) return;
    int is64 = *flagp;
    int s = load_idx_clamped(ei, e, is64, n_nodes);
    int d = load_idx_clamped(ei, (long long)n_edges + e, is64, n_nodes);
    int pos = offs[d] + atomicAdd(&cursor[d], 1);
    pos = pos < 0 ? 0 : (pos >= n_edges ? n_edges - 1 : pos);
    csr[pos] = s;
}

// ---------------------------------------------------------------------------
// Casts
// ---------------------------------------------------------------------------
__global__ __launch_bounds__(256)
void cast_w_kernel(const float* __restrict__ a, const float* __restrict__ b,
                   const float* __restrict__ c, const float* __restrict__ d,
                   __bf16* __restrict__ o) {
    int i = blockIdx.x * 256 + threadIdx.x;
    if (i < FEAT * FEAT) {
        o[i]         = (__bf16)a[i];
        o[4096 + i]  = (__bf16)b[i];
        o[8192 + i]  = (__bf16)c[i];
        o[12288 + i] = (__bf16)d[i];
    }
}

__global__ __launch_bounds__(256)
void cast_x_kernel(const float* __restrict__ x, __bf16* __restrict__ xb, int n4) {
    int i = blockIdx.x * 256 + threadIdx.x;
    if (i < n4) {
        float4 v = ((const float4*)x)[i];
        bf16x4 o;
        o.x = (__bf16)v.x; o.y = (__bf16)v.y; o.z = (__bf16)v.z; o.w = (__bf16)v.w;
        ((bf16x4*)xb)[i] = o;
    }
}

// ---------------------------------------------------------------------------
// Gather (bf16, MLP-unrolled): wave per node; 4 groups of 16 lanes; each
// group issues 4 INDEPENDENT row loads per pass (indices always clamped-valid,
// contributions masked via fmaf) -> 16 outstanding row misses per wave, 4x
// R7's miss-level parallelism. csr read nontemporal (streamed once; keep L2
// for the feature rows).
// ---------------------------------------------------------------------------
__global__ __launch_bounds__(256)
void gather_bf16_kernel(const __bf16* __restrict__ hin, const int* __restrict__ offs,
                        const int* __restrict__ degc, const float* __restrict__ dinv,
                        const int* __restrict__ csr, __bf16* __restrict__ agg,
                        int n_nodes) {
    const int t = threadIdx.x, lane = t & 63, g = lane >> 4, u = lane & 15;
    const int gw = blockIdx.x * 4 + (t >> 6), nw = gridDim.x * 4;
    for (int n = gw; n < n_nodes; n += nw) {
        int rs = offs[n], cnt = degc[n];
        float a0 = 0.f, a1 = 0.f, a2 = 0.f, a3 = 0.f;
        for (int c = 0; c < cnt; c += 64) {
            int chunk = min(64, cnt - c);
            int myid = (lane < chunk) ? (int)__builtin_nontemporal_load(&csr[rs + c + lane]) : 0;
            myid = myid < 0 ? 0 : (myid >= n_nodes ? n_nodes - 1 : myid);
            for (int q = 0; q < chunk; q += 16) {
                int q0 = q + g, q1 = q + g + 4, q2 = q + g + 8, q3 = q + g + 12;
                int s0 = __shfl(myid, q0);
                int s1 = __shfl(myid, q1);
                int s2 = __shfl(myid, q2);
                int s3 = __shfl(myid, q3);
                float m0 = (q0 < chunk) ? 1.f : 0.f;
                float m1 = (q1 < chunk) ? 1.f : 0.f;
                float m2 = (q2 < chunk) ? 1.f : 0.f;
                float m3 = (q3 < chunk) ? 1.f : 0.f;
                bf16x4 v0 = ((const bf16x4*)hin)[(size_t)s0 * 16 + u];
                bf16x4 v1 = ((const bf16x4*)hin)[(size_t)s1 * 16 + u];
                bf16x4 v2 = ((const bf16x4*)hin)[(size_t)s2 * 16 + u];
                bf16x4 v3 = ((const bf16x4*)hin)[(size_t)s3 * 16 + u];
                a0 = fmaf(m0, (float)v0.x, a0); a1 = fmaf(m0, (float)v0.y, a1);
                a2 = fmaf(m0, (float)v0.z, a2); a3 = fmaf(m0, (float)v0.w, a3);
                a0 = fmaf(m1, (float)v1.x, a0); a1 = fmaf(m1, (float)v1.y, a1);
                a2 = fmaf(m1, (float)v1.z, a2); a3 = fmaf(m1, (float)v1.w, a3);
                a0 = fmaf(m2, (float)v2.x, a0); a1 = fmaf(m2, (float)v2.y, a1);
                a2 = fmaf(m2, (float)v2.z, a2); a3 = fmaf(m2, (float)v2.w, a3);
                a0 = fmaf(m3, (float)v3.x, a0); a1 = fmaf(m3, (float)v3.y, a1);
                a2 = fmaf(m3, (float)v3.z, a2); a3 = fmaf(m3, (float)v3.w, a3);
            }
        }
        a0 += __shfl_xor(a0, 16); a1 += __shfl_xor(a1, 16);
        a2 += __shfl_xor(a2, 16); a3 += __shfl_xor(a3, 16);
        a0 += __shfl_xor(a0, 32); a1 += __shfl_xor(a1, 32);
        a2 += __shfl_xor(a2, 32); a3 += __shfl_xor(a3, 32);
        if (g == 0) {
            float di = dinv[n];
            bf16x4 o;
            o.x = (__bf16)(a0 * di); o.y = (__bf16)(a1 * di);
            o.z = (__bf16)(a2 * di); o.w = (__bf16)(a3 * di);
            ((bf16x4*)agg)[(size_t)n * 16 + u] = o;
        }
    }
}

// f32 variant (T3 fallback; same unroll)
__global__ __launch_bounds__(256)
void gather_f32_kernel(const float* __restrict__ xin, const int* __restrict__ offs,
                       const int* __restrict__ degc, const float* __restrict__ dinv,
                       const int* __restrict__ csr, __bf16* __restrict__ agg,
                       int n_nodes) {
    const int t = threadIdx.x, lane = t & 63, g = lane >> 4, u = lane & 15;
    const int gw = blockIdx.x * 4 + (t >> 6), nw = gridDim.x * 4;
    for (int n = gw; n < n_nodes; n += nw) {
        int rs = offs[n], cnt = degc[n];
        float a0 = 0.f, a1 = 0.f, a2 = 0.f, a3 = 0.f;
        for (int c = 0; c < cnt; c += 64) {
            int chunk = min(64, cnt - c);
            int myid = (lane < chunk) ? (int)__builtin_nontemporal_load(&csr[rs + c + lane]) : 0;
            myid = myid < 0 ? 0 : (myid >= n_nodes ? n_nodes - 1 : myid);
            for (int q = 0; q < chunk; q += 16) {
                int q0 = q + g, q1 = q + g + 4, q2 = q + g + 8, q3 = q + g + 12;
                int s0 = __shfl(myid, q0), s1 = __shfl(myid, q1);
                int s2 = __shfl(myid, q2), s3 = __shfl(myid, q3);
                float m0 = (q0 < chunk) ? 1.f : 0.f;
                float m1 = (q1 < chunk) ? 1.f : 0.f;
                float m2 = (q2 < chunk) ? 1.f : 0.f;
                float m3 = (q3 < chunk) ? 1.f : 0.f;
                float4 v0 = ((const float4*)xin)[(size_t)s0 * 16 + u];
                float4 v1 = ((const float4*)xin)[(size_t)s1 * 16 + u];
                float4 v2 = ((const float4*)xin)[(size_t)s2 * 16 + u];
                float4 v3 = ((const float4*)xin)[(size_t)s3 * 16 + u];
                a0 = fmaf(m0, v0.x, a0); a1 = fmaf(m0, v0.y, a1);
                a2 = fmaf(m0, v0.z, a2); a3 = fmaf(m0, v0.w, a3);
                a0 = fmaf(m1, v1.x, a0); a1 = fmaf(m1, v1.y, a1);
                a2 = fmaf(m1, v1.z, a2); a3 = fmaf(m1, v1.w, a3);
                a0 = fmaf(m2, v2.x, a0); a1 = fmaf(m2, v2.y, a1);
                a2 = fmaf(m2, v2.z, a2); a3 = fmaf(m2, v2.w, a3);
                a0 = fmaf(m3, v3.x, a0); a1 = fmaf(m3, v3.y, a1);
                a2 = fmaf(m3, v3.z, a2); a3 = fmaf(m3, v3.w, a3);
            }
        }
        a0 += __shfl_xor(a0, 16); a1 += __shfl_xor(a1, 16);
        a2 += __shfl_xor(a2, 16); a3 += __shfl_xor(a3, 16);
        a0 += __shfl_xor(a0, 32); a1 += __shfl_xor(a1, 32);
        a2 += __shfl_xor(a2, 32); a3 += __shfl_xor(a3, 32);
        if (g == 0) {
            float di = dinv[n];
            bf16x4 o;
            o.x = (__bf16)(a0 * di); o.y = (__bf16)(a1 * di);
            o.z = (__bf16)(a2 * di); o.w = (__bf16)(a3 * di);
            ((bf16x4*)agg)[(size_t)n * 16 + u] = o;
        }
    }
}

// ---------------------------------------------------------------------------
// MFMA GEMMs (16x16x32 bf16; verified fragment layouts).
// ---------------------------------------------------------------------------
__global__ __launch_bounds__(256)
void gemm_l1b_kernel(const __bf16* __restrict__ Ag, const __bf16* __restrict__ xb,
                     const __bf16* __restrict__ Bl, const __bf16* __restrict__ Br,
                     const float* __restrict__ bias,
                     __bf16* __restrict__ hout, int n_nodes) {
    const int t = threadIdx.x, lane = t & 63;
    const int quad = lane >> 4, r16 = lane & 15;
    bf16x8 bl[2][4], br[2][4];
    #pragma unroll
    for (int ks = 0; ks < 2; ++ks)
        #pragma unroll
        for (int ct = 0; ct < 4; ++ct) {
            int f = ct * 16 + r16, k = ks * 32 + quad * 8;
            bl[ks][ct] = *(const bf16x8*)(Bl + f * 64 + k);
            br[ks][ct] = *(const bf16x8*)(Br + f * 64 + k);
        }
    const int m0 = (blockIdx.x * 4 + (t >> 6)) * 16;
    if (m0 >= n_nodes) return;
    int mrow = m0 + r16; if (mrow >= n_nodes) mrow = n_nodes - 1;
    bf16x8 ag[2], ax[2];
    #pragma unroll
    for (int ks = 0; ks < 2; ++ks) {
        ag[ks] = *(const bf16x8*)(Ag + (size_t)mrow * 64 + ks * 32 + quad * 8);
        ax[ks] = *(const bf16x8*)(xb + (size_t)mrow * 64 + ks * 32 + quad * 8);
    }
    #pragma unroll
    for (int ct = 0; ct < 4; ++ct) {
        f32x4 acc = {0.f, 0.f, 0.f, 0.f};
        acc = __builtin_amdgcn_mfma_f32_16x16x32_bf16(ag[0], bl[0][ct], acc, 0, 0, 0);
        acc = __builtin_amdgcn_mfma_f32_16x16x32_bf16(ag[1], bl[1][ct], acc, 0, 0, 0);
        acc = __builtin_amdgcn_mfma_f32_16x16x32_bf16(ax[0], br[0][ct], acc, 0, 0, 0);
        acc = __builtin_amdgcn_mfma_f32_16x16x32_bf16(ax[1], br[1][ct], acc, 0, 0, 0);
        int col = ct * 16 + r16;
        float bv = bias[col];
        #pragma unroll
        for (int rg = 0; rg < 4; ++rg) {
            int n = m0 + quad * 4 + rg;
            if (n < n_nodes) {
                float o = acc[rg] + bv;
                hout[(size_t)n * 64 + col] = (__bf16)fmaxf(o, 0.f);
            }
        }
    }
}

__global__ __launch_bounds__(256)
void gemm_l1_kernel(const __bf16* __restrict__ Ag, const float* __restrict__ xin,
                    const __bf16* __restrict__ Bl, const __bf16* __restrict__ Br,
                    const float* __restrict__ bias,
                    __bf16* __restrict__ hout, int n_nodes) {
    const int t = threadIdx.x, lane = t & 63;
    const int quad = lane >> 4, r16 = lane & 15;
    bf16x8 bl[2][4], br[2][4];
    #pragma unroll
    for (int ks = 0; ks < 2; ++ks)
        #pragma unroll
        for (int ct = 0; ct < 4; ++ct) {
            int f = ct * 16 + r16, k = ks * 32 + quad * 8;
            bl[ks][ct] = *(const bf16x8*)(Bl + f * 64 + k);
            br[ks][ct] = *(const bf16x8*)(Br + f * 64 + k);
        }
    const int m0 = (blockIdx.x * 4 + (t >> 6)) * 16;
    if (m0 >= n_nodes) return;
    int mrow = m0 + r16; if (mrow >= n_nodes) mrow = n_nodes - 1;
    bf16x8 ag[2], ax[2];
    #pragma unroll
    for (int ks = 0; ks < 2; ++ks) {
        ag[ks] = *(const bf16x8*)(Ag + (size_t)mrow * 64 + ks * 32 + quad * 8);
        const float* xr = xin + (size_t)mrow * 64 + ks * 32 + quad * 8;
        float4 p = *(const float4*)xr;
        float4 q = *(const float4*)(xr + 4);
        union { bf16x8 v; __bf16 e[8]; } U;
        U.e[0] = (__bf16)p.x; U.e[1] = (__bf16)p.y; U.e[2] = (__bf16)p.z; U.e[3] = (__bf16)p.w;
        U.e[4] = (__bf16)q.x; U.e[5] = (__bf16)q.y; U.e[6] = (__bf16)q.z; U.e[7] = (__bf16)q.w;
        ax[ks] = U.v;
    }
    #pragma unroll
    for (int ct = 0; ct < 4; ++ct) {
        f32x4 acc = {0.f, 0.f, 0.f, 0.f};
        acc = __builtin_amdgcn_mfma_f32_16x16x32_bf16(ag[0], bl[0][ct], acc, 0, 0, 0);
        acc = __builtin_amdgcn_mfma_f32_16x16x32_bf16(ag[1], bl[1][ct], acc, 0, 0, 0);
        acc = __builtin_amdgcn_mfma_f32_16x16x32_bf16(ax[0], br[0][ct], acc, 0, 0, 0);
        acc = __builtin_amdgcn_mfma_f32_16x16x32_bf16(ax[1], br[1][ct], acc, 0, 0, 0);
        int col = ct * 16 + r16;
        float bv = bias[col];
        #pragma unroll
        for (int rg = 0; rg < 4; ++rg) {
            int n = m0 + quad * 4 + rg;
            if (n < n_nodes) {
                float o = acc[rg] + bv;
                hout[(size_t)n * 64 + col] = (__bf16)fmaxf(o, 0.f);
            }
        }
    }
}

__global__ __launch_bounds__(256)
void gemm_l2_kernel(const __bf16* __restrict__ Ag, const __bf16* __restrict__ Ah,
                    const __bf16* __restrict__ Bl, const __bf16* __restrict__ Br,
                    const float* __restrict__ bias,
                    float* __restrict__ out, int n_nodes) {
    const int t = threadIdx.x, lane = t & 63;
    const int quad = lane >> 4, r16 = lane & 15;
    bf16x8 bl[2][4], br[2][4];
    #pragma unroll
    for (int ks = 0; ks < 2; ++ks)
        #pragma unroll
        for (int ct = 0; ct < 4; ++ct) {
            int f = ct * 16 + r16, k = ks * 32 + quad * 8;
            bl[ks][ct] = *(const bf16x8*)(Bl + f * 64 + k);
            br[ks][ct] = *(const bf16x8*)(Br + f * 64 + k);
        }
    const int m0 = (blockIdx.x * 4 + (t >> 6)) * 16;
    if (m0 >= n_nodes) return;
    int mrow = m0 + r16; if (mrow >= n_nodes) mrow = n_nodes - 1;
    bf16x8 ag[2], ah[2];
    #pragma unroll
    for (int ks = 0; ks < 2; ++ks) {
        ag[ks] = *(const bf16x8*)(Ag + (size_t)mrow * 64 + ks * 32 + quad * 8);
        ah[ks] = *(const bf16x8*)(Ah + (size_t)mrow * 64 + ks * 32 + quad * 8);
    }
    #pragma unroll
    for (int ct = 0; ct < 4; ++ct) {
        f32x4 acc = {0.f, 0.f, 0.f, 0.f};
        acc = __builtin_amdgcn_mfma_f32_16x16x32_bf16(ag[0], bl[0][ct], acc, 0, 0, 0);
        acc = __builtin_amdgcn_mfma_f32_16x16x32_bf16(ag[1], bl[1][ct], acc, 0, 0, 0);
        acc = __builtin_amdgcn_mfma_f32_16x16x32_bf16(ah[0], br[0][ct], acc, 0, 0, 0);
        acc = __builtin_amdgcn_mfma_f32_16x16x32_bf16(ah[1], br[1][ct], acc, 0, 0, 0);
        int col = ct * 16 + r16;
        float bv = bias[col];
        #pragma unroll
        for (int rg = 0; rg < 4; ++rg) {
            int n = m0 + quad * 4 + rg;
            if (n < n_nodes) out[(size_t)n * 64 + col] = acc[rg] + bv;
        }
    }
}

// ---------------------------------------------------------------------------
// T4 fallback (R3): fused LDS kernels.
// ---------------------------------------------------------------------------
__global__ __launch_bounds__(256)
void sage_fused_l1_kernel(const float* __restrict__ xin,
                          const int* __restrict__ offs, const int* __restrict__ degc,
                          const float* __restrict__ deg_inv, const int* __restrict__ csr,
                          const float* __restrict__ Wl, const float* __restrict__ bias,
                          const float* __restrict__ Wr,
                          __bf16* __restrict__ hout, int n_nodes) {
    __shared__ float WlT[FEAT * 65], WrT[FEAT * 65], bsh[FEAT];
    __shared__ float aggS[4][FEAT], selfS[4][FEAT];
    const int t = threadIdx.x;
    #pragma unroll
    for (int p = 0; p < 16; ++p) {
        int i = t + p * 256, j = i >> 6, k = i & 63;
        WlT[k * 65 + j] = Wl[i];
        WrT[k * 65 + j] = Wr[i];
    }
    if (t < FEAT) bsh[t] = bias[t];
    __syncthreads();
    const int w = t >> 6, f = t & 63;
    const int n_groups = (n_nodes + 3) >> 2;
    for (int g = blockIdx.x; g < n_groups; g += gridDim.x) {
        int n = g * 4 + w;
        bool act = (n < n_nodes);
        if (act) {
            int rs = offs[n], cnt = degc[n];
            float acc = 0.f;
            for (int c = 0; c < cnt; c += 64) {
                int chunk = min(64, cnt - c);
                int myid = (f < chunk) ? csr[rs + c + f] : 0;
                #pragma unroll 4
                for (int q = 0; q < chunk; ++q) {
                    int s = __shfl(myid, q);
                    acc += xin[(long long)s * FEAT + f];
                }
            }
            aggS[w][f]  = acc * deg_inv[n];
            selfS[w][f] = xin[(long long)n * FEAT + f];
        }
        __syncthreads();
        if (act) {
            float o = bsh[f];
            #pragma unroll
            for (int k = 0; k < FEAT; ++k) {
                o = fmaf(aggS[w][k],  WlT[k * 65 + f], o);
                o = fmaf(selfS[w][k], WrT[k * 65 + f], o);
            }
            o = fmaxf(o, 0.f);
            hout[(long long)n * FEAT + f] = (__bf16)o;
        }
        __syncthreads();
    }
}

__global__ __launch_bounds__(256)
void sage_fused_l2_kernel(const __bf16* __restrict__ hin,
                          const int* __restrict__ offs, const int* __restrict__ degc,
                          const float* __restrict__ deg_inv, const int* __restrict__ csr,
                          const float* __restrict__ Wl, const float* __restrict__ bias,
                          const float* __restrict__ Wr,
                          float* __restrict__ out, int n_nodes) {
    __shared__ float WlT[FEAT * 65], WrT[FEAT * 65], bsh[FEAT];
    __shared__ float aggS[4][FEAT], selfS[4][FEAT];
    const int t = threadIdx.x;
    #pragma unroll
    for (int p = 0; p < 16; ++p) {
        int i = t + p * 256, j = i >> 6, k = i & 63;
        WlT[k * 65 + j] = Wl[i];
        WrT[k * 65 + j] = Wr[i];
    }
    if (t < FEAT) bsh[t] = bias[t];
    __syncthreads();
    const int w = t >> 6, f = t & 63;
    const int n_groups = (n_nodes + 3) >> 2;
    for (int g = blockIdx.x; g < n_groups; g += gridDim.x) {
        int n = g * 4 + w;
        bool act = (n < n_nodes);
        if (act) {
            int rs = offs[n], cnt = degc[n];
            float acc = 0.f;
            for (int c = 0; c < cnt; c += 64) {
                int chunk = min(64, cnt - c);
                int myid = (f < chunk) ? csr[rs + c + f] : 0;
                #pragma unroll 4
                for (int q = 0; q < chunk; ++q) {
                    int s = __shfl(myid, q);
                    acc += (float)hin[(long long)s * FEAT + f];
                }
            }
            aggS[w][f]  = acc * deg_inv[n];
            selfS[w][f] = (float)hin[(long long)n * FEAT + f];
        }
        __syncthreads();
        if (act) {
            float o = bsh[f];
            #pragma unroll
            for (int k = 0; k < FEAT; ++k) {
                o = fmaf(aggS[w][k],  WlT[k * 65 + f], o);
                o = fmaf(selfS[w][k], WrT[k * 65 + f], o);
            }
            out[(long long)n * FEAT + f] = o;
        }
        __syncthreads();
    }
}

// ---------------------------------------------------------------------------
// Launch
// ---------------------------------------------------------------------------
extern "C" void kernel_launch(void* const* d_in, const int* in_sizes, int n_in,
                              void* d_out, int out_size, void* d_ws, size_t ws_size,
                              hipStream_t stream) {
    const float* x   = (const float*)d_in[0];
    const void*  ei  = d_in[1];
    const float* W1l = (const float*)d_in[2];
    const float* b1  = (const float*)d_in[3];
    const float* W1r = (const float*)d_in[4];
    const float* W2l = (const float*)d_in[5];
    const float* b2  = (const float*)d_in[6];
    const float* W2r = (const float*)d_in[7];
    float* out = (float*)d_out;

    const int n_nodes = in_sizes[0] / FEAT;
    const int n_edges = in_sizes[1] / 2;
    const int nparts  = (n_nodes + 255) / 256;     // <= 512
    const int egrid   = (n_edges + 255) / 256;
    const int NB      = (n_nodes + 511) >> 9;      // buckets of 512 nodes

    char* ws = (char*)d_ws;
    auto al = [](size_t v) { return (v + 255) & ~(size_t)255; };

    // ---- T1 layout (two-level counting sort; <= R7's proven-fit size) ----
    size_t o = 0;
    int*      flag  = (int*)(ws + o);      o += 256;
    int*      degc  = (int*)(ws + o);      o += al((size_t)n_nodes * 4);
    float*    dinv  = (float*)(ws + o);    o += al((size_t)n_nodes * 4);
    int*      offs  = (int*)(ws + o);      o += al((size_t)n_nodes * 4);
    int*      gcnt  = (int*)(ws + o);      o += al(512 * 4);
    int*      gbase = (int*)(ws + o);      o += al(513 * 4);
    int*      gcur  = (int*)(ws + o);      o += al(512 * 4);
    unsigned* B     = (unsigned*)(ws + o); o += al((size_t)n_edges * 4);
    int*      csr   = (int*)(ws + o);      o += al((size_t)n_edges * 4);
    __bf16*   xb    = (__bf16*)(ws + o);   o += al((size_t)n_nodes * FEAT * 2);
    __bf16*   wb    = (__bf16*)(ws + o);   o += al((size_t)4 * FEAT * FEAT * 2);
    __bf16*   agg   = (__bf16*)(ws + o);   o += al((size_t)n_nodes * FEAT * 2);
    __bf16*   h     = (__bf16*)(ws + o);   o += al((size_t)n_nodes * FEAT * 2);
    const size_t needT1 = o;

    // ---- T3 layout (R4, proven) ----
    size_t o3 = 0;
    int*    flag3   = (int*)(ws + o3);    o3 += 256;
    int*    degc3   = (int*)(ws + o3);    o3 += al((size_t)n_nodes * 4);
    float*  dinv3   = (float*)(ws + o3);  o3 += al((size_t)n_nodes * 4);
    int*    offs3   = (int*)(ws + o3);    o3 += al((size_t)n_nodes * 4);
    int*    cursor3 = (int*)(ws + o3);    o3 += al((size_t)n_nodes * 4);
    int*    part3   = (int*)(ws + o3);    o3 += al(2048);
    int*    csr3    = (int*)(ws + o3);    o3 += al((size_t)n_edges * 4);
    const size_t commonEnd3 = o3;
    __bf16* wb3  = (__bf16*)(ws + o3);    o3 += al((size_t)4 * FEAT * FEAT * 2);
    __bf16* agg3 = (__bf16*)(ws + o3);    o3 += al((size_t)n_nodes * FEAT * 2);
    __bf16* h3   = (__bf16*)(ws + o3);    o3 += al((size_t)n_nodes * FEAT * 2);
    const size_t needT3 = o3;

    const int n4 = n_nodes * FEAT / 4;
    const int mgrid = (n_nodes + 63) / 64;
    const int ggrid = 2048;
    const int ntiles = (n_edges + 4095) >> 12;

    if (ws_size >= needT1 && n_nodes <= 131072) {
        zero1_kernel<<<2, 256, 0, stream>>>(gcnt, 512);
        detect_idx_kernel<<<1, 256, 0, stream>>>((const unsigned*)ei, flag);
        bucket_count_kernel<<<512, 256, 0, stream>>>(ei, flag, gcnt, n_edges, n_nodes);
        bucket_scan_kernel<<<1, 512, 0, stream>>>(gcnt, gbase, gcur, n_edges);
        multisplit_kernel<<<ntiles, 256, 0, stream>>>(ei, flag, gcur, B, n_edges, n_nodes);
        cast_x_kernel<<<(n4 + 255) / 256, 256, 0, stream>>>(x, xb, n4);
        cast_w_kernel<<<16, 256, 0, stream>>>(W1l, W1r, W2l, W2r, wb);
        csr_build2_kernel<<<NB, 256, 0, stream>>>(B, gbase, degc, offs, dinv, csr, n_edges, n_nodes);
        gather_bf16_kernel<<<ggrid, 256, 0, stream>>>(xb, offs, degc, dinv, csr, agg, n_nodes);
        gemm_l1b_kernel<<<mgrid, 256, 0, stream>>>(agg, xb, wb, wb + 4096, b1, h, n_nodes);
        gather_bf16_kernel<<<ggrid, 256, 0, stream>>>(h, offs, degc, dinv, csr, agg, n_nodes);
        gemm_l2_kernel<<<mgrid, 256, 0, stream>>>(agg, h, wb + 8192, wb + 12288, b2, out, n_nodes);
    } else if (ws_size >= needT3) {
        zero2_kernel<<<nparts, 256, 0, stream>>>(degc3, cursor3, n_nodes);
        detect_idx_kernel<<<1, 256, 0, stream>>>((const unsigned*)ei, flag3);
        hist_kernel<<<egrid, 256, 0, stream>>>(ei, flag3, degc3, n_edges, n_nodes);
        scan_partial_kernel<<<nparts, 256, 0, stream>>>(degc3, part3, n_nodes);
        scan_top_kernel<<<1, 512, 0, stream>>>(part3, nparts);
        scan_final_kernel<<<nparts, 256, 0, stream>>>(degc3, part3, offs3, dinv3, n_nodes);
        csr_scatter_kernel<<<egrid, 256, 0, stream>>>(ei, flag3, offs3, cursor3, csr3, n_edges, n_nodes);
        cast_w_kernel<<<16, 256, 0, stream>>>(W1l, W1r, W2l, W2r, wb3);
        gather_f32_kernel<<<ggrid, 256, 0, stream>>>(x, offs3, degc3, dinv3, csr3, agg3, n_nodes);
        gemm_l1_kernel<<<mgrid, 256, 0, stream>>>(agg3, x, wb3, wb3 + 4096, b1, h3, n_nodes);
        gather_bf16_kernel<<<ggrid, 256, 0, stream>>>(h3, offs3, degc3, dinv3, csr3, agg3, n_nodes);
        gemm_l2_kernel<<<mgrid, 256, 0, stream>>>(agg3, h3, wb3 + 8192, wb3 + 12288, b2, out, n_nodes);
    } else {
        __bf16* hf = (__bf16*)(ws + commonEnd3);
        zero2_kernel<<<nparts, 256, 0, stream>>>(degc3, cursor3, n_nodes);
        detect_idx_kernel<<<1, 256, 0, stream>>>((const unsigned*)ei, flag3);
        hist_kernel<<<egrid, 256, 0, stream>>>(ei, flag3, degc3, n_edges, n_nodes);
        scan_partial_kernel<<<nparts, 256, 0, stream>>>(degc3, part3, n_nodes);
        scan_top_kernel<<<1, 512, 0, stream>>>(part3, nparts);
        scan_final_kernel<<<nparts, 256, 0, stream>>>(degc3, part3, offs3, dinv3, n_nodes);
        csr_scatter_kernel<<<egrid, 256, 0, stream>>>(ei, flag3, offs3, cursor3, csr3, n_edges, n_nodes);
        const int n_groups = (n_nodes + 3) / 4;
        const int fgrid = n_groups < 4096 ? n_groups : 4096;
        sage_fused_l1_kernel<<<fgrid, 256, 0, stream>>>(x, offs3, degc3, dinv3, csr3,
                                                        W1l, b1, W1r, hf, n_nodes);
        sage_fused_l2_kernel<<<fgrid, 256, 0, stream>>>(hf, offs3, degc3, dinv3, csr3,
                                                        W2l, b2, W2r, out, n_nodes);
    }
}